// Round 3
// baseline (311.855 us; speedup 1.0000x reference)
//
#include <hip/hip_runtime.h>

typedef float          f32x4    __attribute__((ext_vector_type(4)));
typedef float          float8v  __attribute__((ext_vector_type(8)));
typedef unsigned short ushort8v __attribute__((ext_vector_type(8)));
typedef __bf16         bf16x8   __attribute__((ext_vector_type(8)));
typedef __bf16         bf16x4   __attribute__((ext_vector_type(4)));

__device__ __forceinline__ unsigned short f2b(float x) {
  union { __bf16 b; unsigned short u; } v;
  v.b = (__bf16)x;                       // hw v_cvt (RNE) on gfx950
  return v.u;
}
__device__ __forceinline__ float b2f(unsigned short h) {
  union { unsigned u; float f; } v; v.u = ((unsigned)h) << 16;
  return v.f;
}
// drain this wave's LDS ops without touching vmcnt (prefetch stays in flight)
__device__ __forceinline__ void lds_fence() {
  __builtin_amdgcn_wave_barrier();
  asm volatile("s_waitcnt lgkmcnt(0)" ::: "memory");
}

// async global->LDS, 16B per lane; LDS dest = wave-uniform base + lane*16
__device__ __forceinline__ void g2lds16(const unsigned short* g,
                                        unsigned short* l) {
  __builtin_amdgcn_global_load_lds(
      (const __attribute__((address_space(1))) unsigned int*)g,
      (__attribute__((address_space(3))) unsigned int*)l, 16, 0, 0);
}

// ---------------- f32 -> bf16 convert, 8 elems/thread ----------------
__global__ void cvt_kernel(const float* __restrict__ src,
                           unsigned short* __restrict__ dst, int n8) {
  int i = blockIdx.x * 256 + threadIdx.x;
  if (i >= n8) return;
  float8v v = reinterpret_cast<const float8v*>(src)[i];
  ushort8v h;
#pragma unroll
  for (int j = 0; j < 8; ++j) h[j] = f2b(v[j]);
  reinterpret_cast<ushort8v*>(dst)[i] = h;
}

// -------- weight transpose+convert: W(f32)[K][N] -> WT(bf16)[N][K] --------
__global__ __launch_bounds__(256) void wtrans_kernel(
    const float* __restrict__ W, unsigned short* __restrict__ WT,
    int K, int N) {
  __shared__ unsigned short T[64 * 72];
  const int tid = threadIdx.x;
  const int n0 = blockIdx.x * 64, k0 = blockIdx.y * 64;
#pragma unroll
  for (int it = 0; it < 2; ++it) {
    int c = tid + it * 256;               // [0,512)
    int r = c >> 3, cc = c & 7;
    float8v v = *reinterpret_cast<const float8v*>(
        &W[(size_t)(k0 + r) * N + n0 + cc * 8]);
    ushort8v h;
#pragma unroll
    for (int j = 0; j < 8; ++j) h[j] = f2b(v[j]);
    *reinterpret_cast<ushort8v*>(&T[r * 72 + cc * 8]) = h;
  }
  __syncthreads();
#pragma unroll
  for (int it = 0; it < 2; ++it) {
    int c = tid + it * 256;
    int n = c >> 3, kc = c & 7;
    ushort8v y;
#pragma unroll
    for (int j = 0; j < 8; ++j) y[j] = T[(kc * 8 + j) * 72 + n];
    *reinterpret_cast<ushort8v*>(&WT[(size_t)(n0 + n) * K + k0 + kc * 8]) = y;
  }
}

// ---------------- generic gemm_bt (single-buffer) ----------------
template <int TM, typename CT, bool ACC>
__global__ __launch_bounds__(256) void gemm_bt(
    const unsigned short* __restrict__ A, const unsigned short* __restrict__ Bt,
    CT* __restrict__ C, int M, int N, int K) {
  __shared__ unsigned short As[TM * 64];
  __shared__ unsigned short Bs[128 * 64];
  const int tid = threadIdx.x;
  const int m0 = blockIdx.y * TM, n0 = blockIdx.x * 128;
  const int wave = tid >> 6, lane = tid & 63;
  const int wm = (wave >> 1) * (TM / 2), wn = (wave & 1) * 64;
  const int l16 = lane & 15, quad = lane >> 4;
  constexpr int MI = TM / 32;

  f32x4 acc[MI][4];
#pragma unroll
  for (int i = 0; i < MI; ++i)
#pragma unroll
    for (int j = 0; j < 4; ++j)
#pragma unroll
      for (int r = 0; r < 4; ++r) acc[i][j][r] = 0.f;

  for (int k0 = 0; k0 < K; k0 += 64) {
    __syncthreads();
#pragma unroll
    for (int it = 0; it < TM * 8 / 256; ++it) {
      int c = it * 256 + tid;
      int m = c >> 3, kc = (c & 7) ^ (m & 7);
      g2lds16(&A[(size_t)(m0 + m) * K + k0 + kc * 8], &As[c * 8]);
    }
#pragma unroll
    for (int it = 0; it < 4; ++it) {
      int c = it * 256 + tid;
      int n = c >> 3, kc = (c & 7) ^ (n & 7);
      g2lds16(&Bt[(size_t)(n0 + n) * K + k0 + kc * 8], &Bs[c * 8]);
    }
    __syncthreads();

#pragma unroll
    for (int ks = 0; ks < 2; ++ks) {
      bf16x8 af[MI], bfr[4];
#pragma unroll
      for (int mi = 0; mi < MI; ++mi) {
        int m = wm + mi * 16 + l16;
        af[mi] = *reinterpret_cast<const bf16x8*>(
            &As[(m * 8 + ((ks * 4 + quad) ^ (m & 7))) * 8]);
      }
#pragma unroll
      for (int ni = 0; ni < 4; ++ni) {
        int n = wn + ni * 16 + l16;
        bfr[ni] = *reinterpret_cast<const bf16x8*>(
            &Bs[(n * 8 + ((ks * 4 + quad) ^ (n & 7))) * 8]);
      }
#pragma unroll
      for (int mi = 0; mi < MI; ++mi)
#pragma unroll
        for (int ni = 0; ni < 4; ++ni)
          acc[mi][ni] = __builtin_amdgcn_mfma_f32_16x16x32_bf16(
              af[mi], bfr[ni], acc[mi][ni], 0, 0, 0);
    }
  }

#pragma unroll
  for (int mi = 0; mi < MI; ++mi)
#pragma unroll
    for (int ni = 0; ni < 4; ++ni) {
      int row = m0 + wm + mi * 16 + quad * 4;
      int col = n0 + wn + ni * 16 + l16;
#pragma unroll
      for (int r = 0; r < 4; ++r) {
        size_t idx = (size_t)(row + r) * N + col;
        float val = acc[mi][ni][r];
        if constexpr (sizeof(CT) == 2) {
          if constexpr (ACC) val += b2f(C[idx]);
          C[idx] = f2b(val);
        } else {
          if constexpr (ACC) val += C[idx];
          C[idx] = val;
        }
      }
    }
}

// ------- fused GEMM #1: [q_r | k_r | c_kv] = X @ [wqr|wkr|wkvc]^T -------
__global__ __launch_bounds__(256) void gemm_fused3(
    const unsigned short* __restrict__ A, const unsigned short* __restrict__ Bt,
    unsigned short* __restrict__ Cq, unsigned short* __restrict__ Ck,
    unsigned short* __restrict__ Cc, int K) {
  __shared__ unsigned short As[1024 * 8];
  __shared__ unsigned short Bs[1024 * 8];
  const int tid = threadIdx.x;
  const int m0 = blockIdx.y * 128, n0 = blockIdx.x * 128;
  const int wave = tid >> 6, lane = tid & 63;
  const int wm = (wave >> 1) * 64, wn = (wave & 1) * 64;
  const int l16 = lane & 15, quad = lane >> 4;

  f32x4 acc[4][4];
#pragma unroll
  for (int i = 0; i < 4; ++i)
#pragma unroll
    for (int j = 0; j < 4; ++j)
#pragma unroll
      for (int r = 0; r < 4; ++r) acc[i][j][r] = 0.f;

  for (int k0 = 0; k0 < K; k0 += 64) {
    __syncthreads();
#pragma unroll
    for (int it = 0; it < 4; ++it) {
      int c = it * 256 + tid;
      int m = c >> 3, kc = (c & 7) ^ (m & 7);
      g2lds16(&A[(size_t)(m0 + m) * K + k0 + kc * 8], &As[c * 8]);
    }
#pragma unroll
    for (int it = 0; it < 4; ++it) {
      int c = it * 256 + tid;
      int n = c >> 3, kc = (c & 7) ^ (n & 7);
      g2lds16(&Bt[(size_t)(n0 + n) * K + k0 + kc * 8], &Bs[c * 8]);
    }
    __syncthreads();

#pragma unroll
    for (int ks = 0; ks < 2; ++ks) {
      bf16x8 af[4], bfr[4];
#pragma unroll
      for (int mi = 0; mi < 4; ++mi) {
        int m = wm + mi * 16 + l16;
        af[mi] = *reinterpret_cast<const bf16x8*>(
            &As[(m * 8 + ((ks * 4 + quad) ^ (m & 7))) * 8]);
      }
#pragma unroll
      for (int ni = 0; ni < 4; ++ni) {
        int n = wn + ni * 16 + l16;
        bfr[ni] = *reinterpret_cast<const bf16x8*>(
            &Bs[(n * 8 + ((ks * 4 + quad) ^ (n & 7))) * 8]);
      }
#pragma unroll
      for (int mi = 0; mi < 4; ++mi)
#pragma unroll
        for (int ni = 0; ni < 4; ++ni)
          acc[mi][ni] = __builtin_amdgcn_mfma_f32_16x16x32_bf16(
              af[mi], bfr[ni], acc[mi][ni], 0, 0, 0);
    }
  }

  unsigned short* dst;
  int w, cb;
  if (n0 < 1024)      { dst = Cq; w = 1024; cb = 0; }
  else if (n0 < 2048) { dst = Ck; w = 1024; cb = 1024; }
  else                { dst = Cc; w = 128;  cb = 2048; }
#pragma unroll
  for (int mi = 0; mi < 4; ++mi)
#pragma unroll
    for (int ni = 0; ni < 4; ++ni) {
      int row = m0 + wm + mi * 16 + quad * 4;
      int col = n0 - cb + wn + ni * 16 + l16;
#pragma unroll
      for (int r = 0; r < 4; ++r)
        dst[(size_t)(row + r) * w + col] = f2b(acc[mi][ni][r]);
    }
}

// ------- fused GEMM #2: [k_c(acc->ksb) | v_c] = ckv @ [wkc|wvc]^T -------
__global__ __launch_bounds__(256) void gemm_fused2(
    const unsigned short* __restrict__ A, const unsigned short* __restrict__ Bt,
    unsigned short* __restrict__ Ck, unsigned short* __restrict__ Cv, int K) {
  __shared__ unsigned short As[1024 * 8];
  __shared__ unsigned short Bs[1024 * 8];
  const int tid = threadIdx.x;
  const int m0 = blockIdx.y * 128, n0 = blockIdx.x * 128;
  const int wave = tid >> 6, lane = tid & 63;
  const int wm = (wave >> 1) * 64, wn = (wave & 1) * 64;
  const int l16 = lane & 15, quad = lane >> 4;

  f32x4 acc[4][4];
#pragma unroll
  for (int i = 0; i < 4; ++i)
#pragma unroll
    for (int j = 0; j < 4; ++j)
#pragma unroll
      for (int r = 0; r < 4; ++r) acc[i][j][r] = 0.f;

  for (int k0 = 0; k0 < K; k0 += 64) {
    __syncthreads();
#pragma unroll
    for (int it = 0; it < 4; ++it) {
      int c = it * 256 + tid;
      int m = c >> 3, kc = (c & 7) ^ (m & 7);
      g2lds16(&A[(size_t)(m0 + m) * K + k0 + kc * 8], &As[c * 8]);
    }
#pragma unroll
    for (int it = 0; it < 4; ++it) {
      int c = it * 256 + tid;
      int n = c >> 3, kc = (c & 7) ^ (n & 7);
      g2lds16(&Bt[(size_t)(n0 + n) * K + k0 + kc * 8], &Bs[c * 8]);
    }
    __syncthreads();

#pragma unroll
    for (int ks = 0; ks < 2; ++ks) {
      bf16x8 af[4], bfr[4];
#pragma unroll
      for (int mi = 0; mi < 4; ++mi) {
        int m = wm + mi * 16 + l16;
        af[mi] = *reinterpret_cast<const bf16x8*>(
            &As[(m * 8 + ((ks * 4 + quad) ^ (m & 7))) * 8]);
      }
#pragma unroll
      for (int ni = 0; ni < 4; ++ni) {
        int n = wn + ni * 16 + l16;
        bfr[ni] = *reinterpret_cast<const bf16x8*>(
            &Bs[(n * 8 + ((ks * 4 + quad) ^ (n & 7))) * 8]);
      }
#pragma unroll
      for (int mi = 0; mi < 4; ++mi)
#pragma unroll
        for (int ni = 0; ni < 4; ++ni)
          acc[mi][ni] = __builtin_amdgcn_mfma_f32_16x16x32_bf16(
              af[mi], bfr[ni], acc[mi][ni], 0, 0, 0);
    }
  }

  const bool first = (n0 < 1024);
  unsigned short* dst = first ? Ck : Cv;
  int cb = first ? 0 : 1024;
#pragma unroll
  for (int mi = 0; mi < 4; ++mi)
#pragma unroll
    for (int ni = 0; ni < 4; ++ni) {
      int row = m0 + wm + mi * 16 + quad * 4;
      int col = n0 - cb + wn + ni * 16 + l16;
#pragma unroll
      for (int r = 0; r < 4; ++r) {
        size_t idx = (size_t)(row + r) * 1024 + col;
        float val = acc[mi][ni][r];
        if (first) val += b2f(dst[idx]);   // accumulate onto rope'd k_r
        dst[idx] = f2b(val);
      }
    }
}

// ---------------- fused rope transform (in place) ----------------
// q additionally scaled by 0.125 * log2(e) so flash can use raw v_exp (exp2)
__global__ void rope_kernel(unsigned short* __restrict__ qr,
                            unsigned short* __restrict__ kr,
                            const float* __restrict__ tq,
                            const float* __restrict__ tk) {
  int idx = blockIdx.x * 256 + threadIdx.x;
  int i = idx & 31;
  int mh = idx >> 5;       // m*16 + h
  int m = mh >> 4;
  float f = exp2f(-(float)i * (13.287712379549449f / 32.f));  // 10000^(-i/32)
  float cq = cosf(tq[m] * f);
  float ck = cosf(tk[m] * f);
  size_t base = (size_t)mh * 64;
  const float qscale = 0.18033688011112042f;  // 0.125 * log2(e)
  float q1 = b2f(qr[base + i]), q2 = b2f(qr[base + i + 32]);
  float k1 = b2f(kr[base + i]), k2 = b2f(kr[base + i + 32]);
  qr[base + i]      = f2b((q1 * cq - q2 * ck) * qscale);
  qr[base + i + 32] = f2b((q2 * cq + q1 * ck) * qscale);
  kr[base + i]      = f2b(k1 * cq - k2 * ck);
  kr[base + i + 32] = f2b(k2 * cq + k1 * ck);
}

// ---------------- V transpose: [b,l,h,d] -> Vt[b,h,d,l] ----------------
__global__ __launch_bounds__(256) void vtrans_kernel(
    const unsigned short* __restrict__ v, unsigned short* __restrict__ vt,
    int L) {
  __shared__ unsigned short T[64 * 72];
  const int tid = threadIdx.x;
  const int l0 = blockIdx.x * 64, bh = blockIdx.y;
  const size_t inbase = ((size_t)(bh >> 4) * L) * 1024 + (bh & 15) * 64;
  const size_t outbase = (size_t)bh * 64 * L;
#pragma unroll
  for (int it = 0; it < 2; ++it) {
    int c = tid + it * 256;               // [0,512)
    int l = c >> 3, dc = c & 7;
    ushort8v x = *reinterpret_cast<const ushort8v*>(
        &v[inbase + (size_t)(l0 + l) * 1024 + dc * 8]);
    *reinterpret_cast<ushort8v*>(&T[l * 72 + dc * 8]) = x;
  }
  __syncthreads();
#pragma unroll
  for (int it = 0; it < 2; ++it) {
    int c = tid + it * 256;
    int d = c >> 3, lc = c & 7;
    ushort8v y;
#pragma unroll
    for (int j = 0; j < 8; ++j) y[j] = T[(lc * 8 + j) * 72 + d];
    *reinterpret_cast<ushort8v*>(&vt[outbase + (size_t)d * L + l0 + lc * 8]) = y;
  }
}

// ---------- flash v11: 2 waves x 32q, single-buffer, 8 blocks/CU ----------
// LDS-read-BW-bound fix: each wave ingests the full K/V tile from LDS per
// tile regardless of q-count, so give each wave 32 q (2 m-tiles, K/V
// fragments read ONCE, reused across both m-tiles) -> ~1.8x less LDS read
// per unit work vs flash10. 128-thr blocks; LDS trimmed to 20480B
// (K 8K + V 8K + P 2x2K swizzled, single-buffered) so 8 blocks/CU stay
// resident (16 waves/CU = 4/SIMD). Cross-block TLP covers the single-buffer
// stage->drain latency (m114-style overlap).
__global__ __launch_bounds__(128, 4) void flash11_kernel(
    const unsigned short* __restrict__ qs, const unsigned short* __restrict__ ks,
    const unsigned short* __restrict__ vt, unsigned short* __restrict__ o,
    int L) {
  __shared__ unsigned short Ks[512 * 8];      // 64 key x 64 d, swizzled (8KB)
  __shared__ unsigned short Vs[512 * 8];      // 64 d x 64 key, swizzled (8KB)
  __shared__ unsigned short Ps[2][16 * 64];   // per-wave P, XOR slot swz (4KB)
  const int tid = threadIdx.x;
  const int wave = tid >> 6, lane = tid & 63;
  const int l16 = lane & 15, quad = lane >> 4;
  const int bh = blockIdx.y;                  // b*16 + h
  const int qb = blockIdx.x * 64 + wave * 32; // this wave's 32 q rows
  const size_t base = ((size_t)(bh >> 4) * L) * 1024 + (bh & 15) * 64;
  const size_t vtbase = (size_t)bh * 64 * L;

  bf16x8 aq[2][2];
#pragma unroll
  for (int mt = 0; mt < 2; ++mt) {
    size_t qrow = base + (size_t)(qb + mt * 16 + l16) * 1024;
    aq[mt][0] = *reinterpret_cast<const bf16x8*>(&qs[qrow + quad * 8]);
    aq[mt][1] = *reinterpret_cast<const bf16x8*>(&qs[qrow + 32 + quad * 8]);
  }

  ushort8v onesu;
#pragma unroll
  for (int j = 0; j < 8; ++j) onesu[j] = 0x3F80;  // bf16 1.0
  bf16x8 ones = *reinterpret_cast<bf16x8*>(&onesu);

  f32x4 oacc[2][4];
  f32x4 lacc[2];
#pragma unroll
  for (int mt = 0; mt < 2; ++mt) {
#pragma unroll
    for (int r = 0; r < 4; ++r) lacc[mt][r] = 0.f;
#pragma unroll
    for (int nt = 0; nt < 4; ++nt)
#pragma unroll
      for (int r = 0; r < 4; ++r) oacc[mt][nt][r] = 0.f;
  }

  const int T = L / 64;
  for (int t = 0; t < T; ++t) {
    __syncthreads();   // all waves done reading Ks/Vs of tile t-1
    {
      int k0 = t * 64;
#pragma unroll
      for (int it = 0; it < 4; ++it) {
        int c = it * 128 + tid;               // [0,512)
        int key = c >> 3, dc = (c & 7) ^ (key & 7);
        g2lds16(&ks[base + (size_t)(k0 + key) * 1024 + dc * 8], &Ks[c * 8]);
      }
#pragma unroll
      for (int it = 0; it < 4; ++it) {
        int c = it * 128 + tid;
        int d = c >> 3, kc = (c & 7) ^ (d & 7);
        g2lds16(&vt[vtbase + (size_t)d * L + k0 + kc * 8], &Vs[c * 8]);
      }
    }
    __syncthreads();   // compiler drains vmcnt(0) before barrier: tile ready

    // S^T = K Q^T for BOTH m-tiles, K fragments read once.
    // rows = key (quad*4+r), cols = q (l16).
    f32x4 st[2][4];
#pragma unroll
    for (int nt = 0; nt < 4; ++nt) {
      int key = nt * 16 + l16;
      int dc0 = quad ^ (key & 7);
      int dc1 = (4 + quad) ^ (key & 7);
      bf16x8 bk0 = *reinterpret_cast<const bf16x8*>(
          &Ks[(key * 8 + dc0) * 8]);
      bf16x8 bk1 = *reinterpret_cast<const bf16x8*>(
          &Ks[(key * 8 + dc1) * 8]);
#pragma unroll
      for (int mt = 0; mt < 2; ++mt) {
        f32x4 z; z[0] = z[1] = z[2] = z[3] = 0.f;
        z = __builtin_amdgcn_mfma_f32_16x16x32_bf16(bk0, aq[mt][0], z, 0, 0, 0);
        z = __builtin_amdgcn_mfma_f32_16x16x32_bf16(bk1, aq[mt][1], z, 0, 0, 0);
        st[mt][nt] = z;
      }
    }

    // per m-tile: exp2 -> packed P (swizzled b64 writes) -> l via ones-MFMA
    bf16x8 ap[2][2];
#pragma unroll
    for (int mt = 0; mt < 2; ++mt) {
      lds_fence();   // prior ap reads of this wave's P buffer complete
#pragma unroll
      for (int nt = 0; nt < 4; ++nt) {
        bf16x4 w;
#pragma unroll
        for (int r = 0; r < 4; ++r)
          w[r] = (__bf16)__builtin_amdgcn_exp2f(st[mt][nt][r]);
        int slot = (nt * 2 + (quad >> 1)) ^ (l16 & 7);
        *reinterpret_cast<bf16x4*>(
            &Ps[wave][l16 * 64 + slot * 8 + (quad & 1) * 4]) = w;
      }
      lds_fence();   // P writes visible to cross-lane reads
#pragma unroll
      for (int hf = 0; hf < 2; ++hf) {
        int slot = (hf * 4 + quad) ^ (l16 & 7);
        ap[mt][hf] = *reinterpret_cast<const bf16x8*>(
            &Ps[wave][l16 * 64 + slot * 8]);
      }
      lacc[mt] = __builtin_amdgcn_mfma_f32_16x16x32_bf16(ap[mt][0], ones,
                                                         lacc[mt], 0, 0, 0);
      lacc[mt] = __builtin_amdgcn_mfma_f32_16x16x32_bf16(ap[mt][1], ones,
                                                         lacc[mt], 0, 0, 0);
    }

    // O += P V (V fragments read once, used by both m-tiles)
#pragma unroll
    for (int nt = 0; nt < 4; ++nt) {
      int d = nt * 16 + l16;
#pragma unroll
      for (int hf = 0; hf < 2; ++hf) {
        int kc = (hf * 4 + quad) ^ (d & 7);
        bf16x8 bv = *reinterpret_cast<const bf16x8*>(
            &Vs[(d * 8 + kc) * 8]);
#pragma unroll
        for (int mt = 0; mt < 2; ++mt)
          oacc[mt][nt] = __builtin_amdgcn_mfma_f32_16x16x32_bf16(
              ap[mt][hf], bv, oacc[mt][nt], 0, 0, 0);
      }
    }
  }

#pragma unroll
  for (int mt = 0; mt < 2; ++mt)
#pragma unroll
    for (int r = 0; r < 4; ++r) {
      float inv = __builtin_amdgcn_rcpf(lacc[mt][r]);
      int q = qb + mt * 16 + quad * 4 + r;
#pragma unroll
      for (int nt = 0; nt < 4; ++nt)
        o[base + (size_t)q * 1024 + nt * 16 + l16] =
            f2b(oacc[mt][nt][r] * inv);
    }
}

// ---------------- driver ----------------
extern "C" void kernel_launch(void* const* d_in, const int* in_sizes, int n_in,
                              void* d_out, int out_size, void* d_ws, size_t ws_size,
                              hipStream_t stream) {
  const float* X    = (const float*)d_in[0];
  const float* tq   = (const float*)d_in[1];
  const float* tk   = (const float*)d_in[2];
  const float* wkvc = (const float*)d_in[3];
  const float* wkc  = (const float*)d_in[4];
  const float* wvc  = (const float*)d_in[5];
  const float* wqr  = (const float*)d_in[6];
  const float* wkr  = (const float*)d_in[7];
  const float* wo   = (const float*)d_in[8];

  const int D = 1024, DC = 128, L = 2048;
  const int M = in_sizes[0] / D;       // B*L
  const int B = M / L;
  const int NBH = B * 16;
  (void)n_in; (void)out_size; (void)ws_size;

  unsigned short* p = (unsigned short*)d_ws;
  auto take = [&](size_t n) { unsigned short* r = p; p += n; return r; };
  unsigned short* Xb    = take((size_t)M * D);
  unsigned short* qsb   = take((size_t)M * D);
  unsigned short* ksb   = take((size_t)M * D);
  unsigned short* vcb   = take((size_t)M * D);
  unsigned short* ckv   = take((size_t)M * DC);
  unsigned short* Wbig  = take((size_t)(2 * D + DC) * D);   // [wqr|wkr|wkvc]^T
  unsigned short* Wkcvc = take((size_t)(2 * D) * DC);       // [wkc|wvc]^T
  unsigned short* WoT   = take((size_t)D * D);
  unsigned short* vtb   = Xb;   // Xb dead after fused3 gemm
  unsigned short* obuf  = vcb;  // vcb dead after vtrans; flash O lands here

  // prep
  cvt_kernel<<<(M * D / 8 + 255) / 256, 256, 0, stream>>>(X, Xb, M * D / 8);
  auto wt = [&](const float* W, unsigned short* WT, int K, int N) {
    dim3 g(N / 64, K / 64);
    wtrans_kernel<<<g, 256, 0, stream>>>(W, WT, K, N);
  };
  wt(wqr,  Wbig,                          D, D);
  wt(wkr,  Wbig + (size_t)D * D,          D, D);
  wt(wkvc, Wbig + (size_t)2 * D * D,      D, DC);
  wt(wkc,  Wkcvc,                         DC, D);
  wt(wvc,  Wkcvc + (size_t)D * DC,        DC, D);
  wt(wo,   WoT,                           D, D);

  {
    dim3 g((2 * D + DC) / 128, M / 128);                   // (17, 32)
    gemm_fused3<<<g, 256, 0, stream>>>(Xb, Wbig, qsb, ksb, ckv, D);
  }
  rope_kernel<<<(M * 512) / 256, 256, 0, stream>>>(qsb, ksb, tq, tk);
  {
    dim3 g(2 * D / 128, M / 128);                          // (16, 32)
    gemm_fused2<<<g, 256, 0, stream>>>(ckv, Wkcvc, ksb, vcb, DC);
  }

  dim3 tg(L / 64, NBH);
  vtrans_kernel<<<tg, 256, 0, stream>>>(vcb, vtb, L);

  dim3 fg(L / 64, NBH);                                    // (32, 32)
  flash11_kernel<<<fg, 128, 0, stream>>>(qsb, ksb, vtb, obuf, L);

  {
    dim3 g(D / 128, M / 64);                               // (8, 64)
    gemm_bt<64, float, false><<<g, 256, 0, stream>>>(
        obuf, WoT, (float*)d_out, M, D, D);
  }
}

// Round 5
// 233.852 us; speedup vs baseline: 1.3336x; 1.3336x over previous
//
#include <hip/hip_runtime.h>

typedef float          f32x4    __attribute__((ext_vector_type(4)));
typedef float          float8v  __attribute__((ext_vector_type(8)));
typedef unsigned short ushort8v __attribute__((ext_vector_type(8)));
typedef unsigned short ushort4v __attribute__((ext_vector_type(4)));
typedef __bf16         bf16x8   __attribute__((ext_vector_type(8)));

__device__ __forceinline__ unsigned short f2b(float x) {
  union { __bf16 b; unsigned short u; } v;
  v.b = (__bf16)x;                       // hw v_cvt (RNE) on gfx950
  return v.u;
}
__device__ __forceinline__ float b2f(unsigned short h) {
  union { unsigned u; float f; } v; v.u = ((unsigned)h) << 16;
  return v.f;
}

// async global->LDS, 16B per lane; LDS dest = wave-uniform base + lane*16
__device__ __forceinline__ void g2lds16(const unsigned short* g,
                                        unsigned short* l) {
  __builtin_amdgcn_global_load_lds(
      (const __attribute__((address_space(1))) unsigned int*)g,
      (__attribute__((address_space(3))) unsigned int*)l, 16, 0, 0);
}

// ---------------- f32 -> bf16 convert, 8 elems/thread ----------------
__global__ void cvt_kernel(const float* __restrict__ src,
                           unsigned short* __restrict__ dst, int n8) {
  int i = blockIdx.x * 256 + threadIdx.x;
  if (i >= n8) return;
  float8v v = reinterpret_cast<const float8v*>(src)[i];
  ushort8v h;
#pragma unroll
  for (int j = 0; j < 8; ++j) h[j] = f2b(v[j]);
  reinterpret_cast<ushort8v*>(dst)[i] = h;
}

// -------- weight transpose+convert: W(f32)[K][N] -> WT(bf16)[N][K] --------
__global__ __launch_bounds__(256) void wtrans_kernel(
    const float* __restrict__ W, unsigned short* __restrict__ WT,
    int K, int N) {
  __shared__ unsigned short T[64 * 72];
  const int tid = threadIdx.x;
  const int n0 = blockIdx.x * 64, k0 = blockIdx.y * 64;
#pragma unroll
  for (int it = 0; it < 2; ++it) {
    int c = tid + it * 256;               // [0,512)
    int r = c >> 3, cc = c & 7;
    float8v v = *reinterpret_cast<const float8v*>(
        &W[(size_t)(k0 + r) * N + n0 + cc * 8]);
    ushort8v h;
#pragma unroll
    for (int j = 0; j < 8; ++j) h[j] = f2b(v[j]);
    *reinterpret_cast<ushort8v*>(&T[r * 72 + cc * 8]) = h;
  }
  __syncthreads();
#pragma unroll
  for (int it = 0; it < 2; ++it) {
    int c = tid + it * 256;
    int n = c >> 3, kc = c & 7;
    ushort8v y;
#pragma unroll
    for (int j = 0; j < 8; ++j) y[j] = T[(kc * 8 + j) * 72 + n];
    *reinterpret_cast<ushort8v*>(&WT[(size_t)(n0 + n) * K + k0 + kc * 8]) = y;
  }
}

// ---------------- generic gemm_bt (single-buffer) ----------------
template <int TM, typename CT, bool ACC>
__global__ __launch_bounds__(256) void gemm_bt(
    const unsigned short* __restrict__ A, const unsigned short* __restrict__ Bt,
    CT* __restrict__ C, int M, int N, int K) {
  __shared__ unsigned short As[TM * 64];
  __shared__ unsigned short Bs[128 * 64];
  const int tid = threadIdx.x;
  const int m0 = blockIdx.y * TM, n0 = blockIdx.x * 128;
  const int wave = tid >> 6, lane = tid & 63;
  const int wm = (wave >> 1) * (TM / 2), wn = (wave & 1) * 64;
  const int l16 = lane & 15, quad = lane >> 4;
  constexpr int MI = TM / 32;

  f32x4 acc[MI][4];
#pragma unroll
  for (int i = 0; i < MI; ++i)
#pragma unroll
    for (int j = 0; j < 4; ++j)
#pragma unroll
      for (int r = 0; r < 4; ++r) acc[i][j][r] = 0.f;

  for (int k0 = 0; k0 < K; k0 += 64) {
    __syncthreads();
#pragma unroll
    for (int it = 0; it < TM * 8 / 256; ++it) {
      int c = it * 256 + tid;
      int m = c >> 3, kc = (c & 7) ^ (m & 7);
      g2lds16(&A[(size_t)(m0 + m) * K + k0 + kc * 8], &As[c * 8]);
    }
#pragma unroll
    for (int it = 0; it < 4; ++it) {
      int c = it * 256 + tid;
      int n = c >> 3, kc = (c & 7) ^ (n & 7);
      g2lds16(&Bt[(size_t)(n0 + n) * K + k0 + kc * 8], &Bs[c * 8]);
    }
    __syncthreads();

#pragma unroll
    for (int ks = 0; ks < 2; ++ks) {
      bf16x8 af[MI], bfr[4];
#pragma unroll
      for (int mi = 0; mi < MI; ++mi) {
        int m = wm + mi * 16 + l16;
        af[mi] = *reinterpret_cast<const bf16x8*>(
            &As[(m * 8 + ((ks * 4 + quad) ^ (m & 7))) * 8]);
      }
#pragma unroll
      for (int ni = 0; ni < 4; ++ni) {
        int n = wn + ni * 16 + l16;
        bfr[ni] = *reinterpret_cast<const bf16x8*>(
            &Bs[(n * 8 + ((ks * 4 + quad) ^ (n & 7))) * 8]);
      }
#pragma unroll
      for (int mi = 0; mi < MI; ++mi)
#pragma unroll
        for (int ni = 0; ni < 4; ++ni)
          acc[mi][ni] = __builtin_amdgcn_mfma_f32_16x16x32_bf16(
              af[mi], bfr[ni], acc[mi][ni], 0, 0, 0);
    }
  }

#pragma unroll
  for (int mi = 0; mi < MI; ++mi)
#pragma unroll
    for (int ni = 0; ni < 4; ++ni) {
      int row = m0 + wm + mi * 16 + quad * 4;
      int col = n0 + wn + ni * 16 + l16;
#pragma unroll
      for (int r = 0; r < 4; ++r) {
        size_t idx = (size_t)(row + r) * N + col;
        float val = acc[mi][ni][r];
        if constexpr (sizeof(CT) == 2) {
          if constexpr (ACC) val += b2f(C[idx]);
          C[idx] = f2b(val);
        } else {
          if constexpr (ACC) val += C[idx];
          C[idx] = val;
        }
      }
    }
}

// ------- fused GEMM #1: [q_r | k_r | c_kv] = X @ [wqr|wkr|wkvc]^T -------
__global__ __launch_bounds__(256) void gemm_fused3(
    const unsigned short* __restrict__ A, const unsigned short* __restrict__ Bt,
    unsigned short* __restrict__ Cq, unsigned short* __restrict__ Ck,
    unsigned short* __restrict__ Cc, int K) {
  __shared__ unsigned short As[1024 * 8];
  __shared__ unsigned short Bs[1024 * 8];
  const int tid = threadIdx.x;
  const int m0 = blockIdx.y * 128, n0 = blockIdx.x * 128;
  const int wave = tid >> 6, lane = tid & 63;
  const int wm = (wave >> 1) * 64, wn = (wave & 1) * 64;
  const int l16 = lane & 15, quad = lane >> 4;

  f32x4 acc[4][4];
#pragma unroll
  for (int i = 0; i < 4; ++i)
#pragma unroll
    for (int j = 0; j < 4; ++j)
#pragma unroll
      for (int r = 0; r < 4; ++r) acc[i][j][r] = 0.f;

  for (int k0 = 0; k0 < K; k0 += 64) {
    __syncthreads();
#pragma unroll
    for (int it = 0; it < 4; ++it) {
      int c = it * 256 + tid;
      int m = c >> 3, kc = (c & 7) ^ (m & 7);
      g2lds16(&A[(size_t)(m0 + m) * K + k0 + kc * 8], &As[c * 8]);
    }
#pragma unroll
    for (int it = 0; it < 4; ++it) {
      int c = it * 256 + tid;
      int n = c >> 3, kc = (c & 7) ^ (n & 7);
      g2lds16(&Bt[(size_t)(n0 + n) * K + k0 + kc * 8], &Bs[c * 8]);
    }
    __syncthreads();

#pragma unroll
    for (int ks = 0; ks < 2; ++ks) {
      bf16x8 af[4], bfr[4];
#pragma unroll
      for (int mi = 0; mi < 4; ++mi) {
        int m = wm + mi * 16 + l16;
        af[mi] = *reinterpret_cast<const bf16x8*>(
            &As[(m * 8 + ((ks * 4 + quad) ^ (m & 7))) * 8]);
      }
#pragma unroll
      for (int ni = 0; ni < 4; ++ni) {
        int n = wn + ni * 16 + l16;
        bfr[ni] = *reinterpret_cast<const bf16x8*>(
            &Bs[(n * 8 + ((ks * 4 + quad) ^ (n & 7))) * 8]);
      }
#pragma unroll
      for (int mi = 0; mi < 4; ++mi)
#pragma unroll
        for (int ni = 0; ni < 4; ++ni)
          acc[mi][ni] = __builtin_amdgcn_mfma_f32_16x16x32_bf16(
              af[mi], bfr[ni], acc[mi][ni], 0, 0, 0);
    }
  }

  unsigned short* dst;
  int w, cb;
  if (n0 < 1024)      { dst = Cq; w = 1024; cb = 0; }
  else if (n0 < 2048) { dst = Ck; w = 1024; cb = 1024; }
  else                { dst = Cc; w = 128;  cb = 2048; }
#pragma unroll
  for (int mi = 0; mi < 4; ++mi)
#pragma unroll
    for (int ni = 0; ni < 4; ++ni) {
      int row = m0 + wm + mi * 16 + quad * 4;
      int col = n0 - cb + wn + ni * 16 + l16;
#pragma unroll
      for (int r = 0; r < 4; ++r)
        dst[(size_t)(row + r) * w + col] = f2b(acc[mi][ni][r]);
    }
}

// ------- fused GEMM #2: [k_c(acc->ksb) | v_c] = ckv @ [wkc|wvc]^T -------
__global__ __launch_bounds__(256) void gemm_fused2(
    const unsigned short* __restrict__ A, const unsigned short* __restrict__ Bt,
    unsigned short* __restrict__ Ck, unsigned short* __restrict__ Cv, int K) {
  __shared__ unsigned short As[1024 * 8];
  __shared__ unsigned short Bs[1024 * 8];
  const int tid = threadIdx.x;
  const int m0 = blockIdx.y * 128, n0 = blockIdx.x * 128;
  const int wave = tid >> 6, lane = tid & 63;
  const int wm = (wave >> 1) * 64, wn = (wave & 1) * 64;
  const int l16 = lane & 15, quad = lane >> 4;

  f32x4 acc[4][4];
#pragma unroll
  for (int i = 0; i < 4; ++i)
#pragma unroll
    for (int j = 0; j < 4; ++j)
#pragma unroll
      for (int r = 0; r < 4; ++r) acc[i][j][r] = 0.f;

  for (int k0 = 0; k0 < K; k0 += 64) {
    __syncthreads();
#pragma unroll
    for (int it = 0; it < 4; ++it) {
      int c = it * 256 + tid;
      int m = c >> 3, kc = (c & 7) ^ (m & 7);
      g2lds16(&A[(size_t)(m0 + m) * K + k0 + kc * 8], &As[c * 8]);
    }
#pragma unroll
    for (int it = 0; it < 4; ++it) {
      int c = it * 256 + tid;
      int n = c >> 3, kc = (c & 7) ^ (n & 7);
      g2lds16(&Bt[(size_t)(n0 + n) * K + k0 + kc * 8], &Bs[c * 8]);
    }
    __syncthreads();

#pragma unroll
    for (int ks = 0; ks < 2; ++ks) {
      bf16x8 af[4], bfr[4];
#pragma unroll
      for (int mi = 0; mi < 4; ++mi) {
        int m = wm + mi * 16 + l16;
        af[mi] = *reinterpret_cast<const bf16x8*>(
            &As[(m * 8 + ((ks * 4 + quad) ^ (m & 7))) * 8]);
      }
#pragma unroll
      for (int ni = 0; ni < 4; ++ni) {
        int n = wn + ni * 16 + l16;
        bfr[ni] = *reinterpret_cast<const bf16x8*>(
            &Bs[(n * 8 + ((ks * 4 + quad) ^ (n & 7))) * 8]);
      }
#pragma unroll
      for (int mi = 0; mi < 4; ++mi)
#pragma unroll
        for (int ni = 0; ni < 4; ++ni)
          acc[mi][ni] = __builtin_amdgcn_mfma_f32_16x16x32_bf16(
              af[mi], bfr[ni], acc[mi][ni], 0, 0, 0);
    }
  }

  const bool first = (n0 < 1024);
  unsigned short* dst = first ? Ck : Cv;
  int cb = first ? 0 : 1024;
#pragma unroll
  for (int mi = 0; mi < 4; ++mi)
#pragma unroll
    for (int ni = 0; ni < 4; ++ni) {
      int row = m0 + wm + mi * 16 + quad * 4;
      int col = n0 - cb + wn + ni * 16 + l16;
#pragma unroll
      for (int r = 0; r < 4; ++r) {
        size_t idx = (size_t)(row + r) * 1024 + col;
        float val = acc[mi][ni][r];
        if (first) val += b2f(dst[idx]);   // accumulate onto rope'd k_r
        dst[idx] = f2b(val);
      }
    }
}

// ---------------- fused rope transform (in place) ----------------
// q additionally scaled by 0.125 * log2(e) so flash can use raw v_exp (exp2)
__global__ void rope_kernel(unsigned short* __restrict__ qr,
                            unsigned short* __restrict__ kr,
                            const float* __restrict__ tq,
                            const float* __restrict__ tk) {
  int idx = blockIdx.x * 256 + threadIdx.x;
  int i = idx & 31;
  int mh = idx >> 5;       // m*16 + h
  int m = mh >> 4;
  float f = exp2f(-(float)i * (13.287712379549449f / 32.f));  // 10000^(-i/32)
  float cq = cosf(tq[m] * f);
  float ck = cosf(tk[m] * f);
  size_t base = (size_t)mh * 64;
  const float qscale = 0.18033688011112042f;  // 0.125 * log2(e)
  float q1 = b2f(qr[base + i]), q2 = b2f(qr[base + i + 32]);
  float k1 = b2f(kr[base + i]), k2 = b2f(kr[base + i + 32]);
  qr[base + i]      = f2b((q1 * cq - q2 * ck) * qscale);
  qr[base + i + 32] = f2b((q2 * cq + q1 * ck) * qscale);
  kr[base + i]      = f2b(k1 * cq - k2 * ck);
  kr[base + i + 32] = f2b(k2 * cq + k1 * ck);
}

// ------ V transpose + key-permute: [b,l,h,d] -> Vt[b,h,d,sigma^-1(l)] ------
// flash13 consumes P in-register with the fixed key permutation
// sigma(slot): phys-key bits [4:2] = rot-right of slot bits [4:2]
//   slot = [k5 Q1 Q0 w1 w0 b] -> phys = [k5 w1 Q1 Q0 w0 b].
// So V's key axis (within each 64-key tile) is stored at sigma^-1(key):
//   s = [k5 | k3 | k2 | k4 | k1 k0]  (bit4=k3, bit3=k2, bit2=k4).
// Each 8-key run splits into two 4-key (8B) writes.
__global__ __launch_bounds__(256) void vtrans_kernel(
    const unsigned short* __restrict__ v, unsigned short* __restrict__ vt,
    int L) {
  __shared__ unsigned short T[64 * 72];
  const int tid = threadIdx.x;
  const int l0 = blockIdx.x * 64, bh = blockIdx.y;
  const size_t inbase = ((size_t)(bh >> 4) * L) * 1024 + (bh & 15) * 64;
  const size_t outbase = (size_t)bh * 64 * L;
#pragma unroll
  for (int it = 0; it < 2; ++it) {
    int c = tid + it * 256;               // [0,512)
    int l = c >> 3, dc = c & 7;
    ushort8v x = *reinterpret_cast<const ushort8v*>(
        &v[inbase + (size_t)(l0 + l) * 1024 + dc * 8]);
    *reinterpret_cast<ushort8v*>(&T[l * 72 + dc * 8]) = x;
  }
  __syncthreads();
#pragma unroll
  for (int it = 0; it < 2; ++it) {
    int c = tid + it * 256;
    int d = c >> 3, lc = c & 7;            // keys lc*8 .. lc*8+7
    ushort4v ylo, yhi;
#pragma unroll
    for (int j = 0; j < 4; ++j) ylo[j] = T[(lc * 8 + j) * 72 + d];
#pragma unroll
    for (int j = 0; j < 4; ++j) yhi[j] = T[(lc * 8 + 4 + j) * 72 + d];
    // sigma^-1 of keys {lc*8 + j}: j=0..3 -> bs + j ; j=4..7 -> bs + 8 + j-4
    int bs = ((lc >> 2) << 5) | ((lc & 1) << 4) | (((lc >> 1) & 1) << 2);
    size_t row = outbase + (size_t)d * L + l0;
    *reinterpret_cast<ushort4v*>(&vt[row + bs]) = ylo;
    *reinterpret_cast<ushort4v*>(&vt[row + bs + 8]) = yhi;
  }
}

// ---------- flash v13: in-register P via key-permutation (no shuffles) ----
// 256 thr, 4 waves x 16q, dbuf K/V (32KB LDS), 1024 blocks -> 4 blocks/CU,
// 16 waves/CU. S^T via mfma(K,Q): lane(l16,quad) holds P[q=l16][key=nt*16+
// quad*4+r]. The PV A-frag is assembled by pure register renaming:
//   ap[hf].word[w] = P pair (nt=2hf+(w>>1), r=2*(w&1)+{0,1})
// which realizes key-permutation sigma; V was stored with sigma^-1 applied
// by vtrans, so P and V agree. No P LDS roundtrip, no fences, no permlane.
// Numerics identical to flash10 (plain (__bf16) casts).
__global__ __launch_bounds__(256) void flash13_kernel(
    const unsigned short* __restrict__ qs, const unsigned short* __restrict__ ks,
    const unsigned short* __restrict__ vt, unsigned short* __restrict__ o,
    int L) {
  __shared__ unsigned short Ks[2][512 * 8];   // 64 key x 64 d, swizzled (16KB)
  __shared__ unsigned short Vs[2][512 * 8];   // 64 d x 64 key(perm), swz (16KB)
  const int tid = threadIdx.x;
  const int wave = tid >> 6, lane = tid & 63;
  const int l16 = lane & 15, quad = lane >> 4;
  const int bh = blockIdx.y;                  // b*16 + h
  const int qb = blockIdx.x * 64 + wave * 16; // this wave's m-tile
  const size_t base = ((size_t)(bh >> 4) * L) * 1024 + (bh & 15) * 64;
  const size_t vtbase = (size_t)bh * 64 * L;

  bf16x8 aq[2];
  {
    size_t qrow = base + (size_t)(qb + l16) * 1024;
    aq[0] = *reinterpret_cast<const bf16x8*>(&qs[qrow + quad * 8]);
    aq[1] = *reinterpret_cast<const bf16x8*>(&qs[qrow + 32 + quad * 8]);
  }

  ushort8v onesu;
#pragma unroll
  for (int j = 0; j < 8; ++j) onesu[j] = 0x3F80;  // bf16 1.0
  bf16x8 ones = *reinterpret_cast<bf16x8*>(&onesu);

  f32x4 oacc[4];
  f32x4 lacc;
#pragma unroll
  for (int r = 0; r < 4; ++r) lacc[r] = 0.f;
#pragma unroll
  for (int nt = 0; nt < 4; ++nt)
#pragma unroll
    for (int r = 0; r < 4; ++r) oacc[nt][r] = 0.f;

  const int T = L / 64;
  // prologue: stage tile 0 (256 threads -> 2 its per buffer)
#pragma unroll
  for (int it = 0; it < 2; ++it) {
    int c = it * 256 + tid;                   // [0,512)
    int key = c >> 3, dc = (c & 7) ^ (key & 7);
    g2lds16(&ks[base + (size_t)key * 1024 + dc * 8], &Ks[0][c * 8]);
  }
#pragma unroll
  for (int it = 0; it < 2; ++it) {
    int c = it * 256 + tid;
    int d = c >> 3, kc = (c & 7) ^ (d & 7);
    g2lds16(&vt[vtbase + (size_t)d * L + kc * 8], &Vs[0][c * 8]);
  }

  for (int t = 0; t < T; ++t) {
    __syncthreads();   // drains stage(t); prior-buf readers done
    if (t + 1 < T) {
      int k0 = (t + 1) * 64, nb = (t + 1) & 1;
#pragma unroll
      for (int it = 0; it < 2; ++it) {
        int c = it * 256 + tid;
        int key = c >> 3, dc = (c & 7) ^ (key & 7);
        g2lds16(&ks[base + (size_t)(k0 + key) * 1024 + dc * 8], &Ks[nb][c * 8]);
      }
#pragma unroll
      for (int it = 0; it < 2; ++it) {
        int c = it * 256 + tid;
        int d = c >> 3, kc = (c & 7) ^ (d & 7);
        g2lds16(&vt[vtbase + (size_t)d * L + k0 + kc * 8], &Vs[nb][c * 8]);
      }
    }
    const int cb = t & 1;

    // S^T = K Q^T: rows = key (quad*4+r), cols = q (l16)
    f32x4 st[4];
#pragma unroll
    for (int nt = 0; nt < 4; ++nt) {
      int key = nt * 16 + l16;
      int dc0 = quad ^ (key & 7);
      int dc1 = (4 + quad) ^ (key & 7);
      bf16x8 bk0 = *reinterpret_cast<const bf16x8*>(
          &Ks[cb][(key * 8 + dc0) * 8]);
      bf16x8 bk1 = *reinterpret_cast<const bf16x8*>(
          &Ks[cb][(key * 8 + dc1) * 8]);
      f32x4 z; z[0] = z[1] = z[2] = z[3] = 0.f;
      z = __builtin_amdgcn_mfma_f32_16x16x32_bf16(bk0, aq[0], z, 0, 0, 0);
      z = __builtin_amdgcn_mfma_f32_16x16x32_bf16(bk1, aq[1], z, 0, 0, 0);
      st[nt] = z;
    }

    // exp2 -> ap frags by pure register renaming (key-permutation sigma):
    // ap[hf] elems (2w, 2w+1) = exp2(st[2hf + (w>>1)][2*(w&1) + {0,1}])
    bf16x8 ap[2];
#pragma unroll
    for (int hf = 0; hf < 2; ++hf)
#pragma unroll
      for (int w = 0; w < 4; ++w) {
        int nt = 2 * hf + (w >> 1), p = w & 1;
        ap[hf][2 * w]     = (__bf16)__builtin_amdgcn_exp2f(st[nt][2 * p]);
        ap[hf][2 * w + 1] = (__bf16)__builtin_amdgcn_exp2f(st[nt][2 * p + 1]);
      }

    lacc = __builtin_amdgcn_mfma_f32_16x16x32_bf16(ap[0], ones, lacc, 0, 0, 0);
    lacc = __builtin_amdgcn_mfma_f32_16x16x32_bf16(ap[1], ones, lacc, 0, 0, 0);

    // O += P V (V key axis pre-permuted by vtrans to match sigma)
#pragma unroll
    for (int nt = 0; nt < 4; ++nt) {
      int d = nt * 16 + l16;
#pragma unroll
      for (int hf = 0; hf < 2; ++hf) {
        int kc = (hf * 4 + quad) ^ (d & 7);
        bf16x8 bv = *reinterpret_cast<const bf16x8*>(
            &Vs[cb][(d * 8 + kc) * 8]);
        oacc[nt] = __builtin_amdgcn_mfma_f32_16x16x32_bf16(
            ap[hf], bv, oacc[nt], 0, 0, 0);
      }
    }
  }

#pragma unroll
  for (int r = 0; r < 4; ++r) {
    float inv = __builtin_amdgcn_rcpf(lacc[r]);
    int q = qb + quad * 4 + r;
#pragma unroll
    for (int nt = 0; nt < 4; ++nt)
      o[base + (size_t)q * 1024 + nt * 16 + l16] = f2b(oacc[nt][r] * inv);
  }
}

// ---------------- driver ----------------
extern "C" void kernel_launch(void* const* d_in, const int* in_sizes, int n_in,
                              void* d_out, int out_size, void* d_ws, size_t ws_size,
                              hipStream_t stream) {
  const float* X    = (const float*)d_in[0];
  const float* tq   = (const float*)d_in[1];
  const float* tk   = (const float*)d_in[2];
  const float* wkvc = (const float*)d_in[3];
  const float* wkc  = (const float*)d_in[4];
  const float* wvc  = (const float*)d_in[5];
  const float* wqr  = (const float*)d_in[6];
  const float* wkr  = (const float*)d_in[7];
  const float* wo   = (const float*)d_in[8];

  const int D = 1024, DC = 128, L = 2048;
  const int M = in_sizes[0] / D;       // B*L
  const int B = M / L;
  const int NBH = B * 16;
  (void)n_in; (void)out_size; (void)ws_size;

  unsigned short* p = (unsigned short*)d_ws;
  auto take = [&](size_t n) { unsigned short* r = p; p += n; return r; };
  unsigned short* Xb    = take((size_t)M * D);
  unsigned short* qsb   = take((size_t)M * D);
  unsigned short* ksb   = take((size_t)M * D);
  unsigned short* vcb   = take((size_t)M * D);
  unsigned short* ckv   = take((size_t)M * DC);
  unsigned short* Wbig  = take((size_t)(2 * D + DC) * D);   // [wqr|wkr|wkvc]^T
  unsigned short* Wkcvc = take((size_t)(2 * D) * DC);       // [wkc|wvc]^T
  unsigned short* WoT   = take((size_t)D * D);
  unsigned short* vtb   = Xb;   // Xb dead after fused3 gemm
  unsigned short* obuf  = vcb;  // vcb dead after vtrans; flash O lands here

  // prep
  cvt_kernel<<<(M * D / 8 + 255) / 256, 256, 0, stream>>>(X, Xb, M * D / 8);
  auto wt = [&](const float* W, unsigned short* WT, int K, int N) {
    dim3 g(N / 64, K / 64);
    wtrans_kernel<<<g, 256, 0, stream>>>(W, WT, K, N);
  };
  wt(wqr,  Wbig,                          D, D);
  wt(wkr,  Wbig + (size_t)D * D,          D, D);
  wt(wkvc, Wbig + (size_t)2 * D * D,      D, DC);
  wt(wkc,  Wkcvc,                         DC, D);
  wt(wvc,  Wkcvc + (size_t)D * DC,        DC, D);
  wt(wo,   WoT,                           D, D);

  {
    dim3 g((2 * D + DC) / 128, M / 128);                   // (17, 32)
    gemm_fused3<<<g, 256, 0, stream>>>(Xb, Wbig, qsb, ksb, ckv, D);
  }
  rope_kernel<<<(M * 512) / 256, 256, 0, stream>>>(qsb, ksb, tq, tk);
  {
    dim3 g(2 * D / 128, M / 128);                          // (16, 32)
    gemm_fused2<<<g, 256, 0, stream>>>(ckv, Wkcvc, ksb, vcb, DC);
  }

  dim3 tg(L / 64, NBH);
  vtrans_kernel<<<tg, 256, 0, stream>>>(vcb, vtb, L);

  dim3 fg(L / 64, NBH);                                    // (32, 32)
  flash13_kernel<<<fg, 256, 0, stream>>>(qsb, ksb, vtb, obuf, L);

  {
    dim3 g(D / 128, M / 64);                               // (8, 64)
    gemm_bt<64, float, false><<<g, 256, 0, stream>>>(
        obuf, WoT, (float*)d_out, M, D, D);
  }
}

// Round 6
// 226.028 us; speedup vs baseline: 1.3797x; 1.0346x over previous
//
#include <hip/hip_runtime.h>

typedef float          f32x4    __attribute__((ext_vector_type(4)));
typedef float          float8v  __attribute__((ext_vector_type(8)));
typedef unsigned short ushort8v __attribute__((ext_vector_type(8)));
typedef __bf16         bf16x8   __attribute__((ext_vector_type(8)));

__device__ __forceinline__ unsigned short f2b(float x) {
  union { __bf16 b; unsigned short u; } v;
  v.b = (__bf16)x;                       // hw v_cvt (RNE) on gfx950
  return v.u;
}
__device__ __forceinline__ float b2f(unsigned short h) {
  union { unsigned u; float f; } v; v.u = ((unsigned)h) << 16;
  return v.f;
}

// async global->LDS, 16B per lane; LDS dest = wave-uniform base + lane*16
__device__ __forceinline__ void g2lds16(const unsigned short* g,
                                        unsigned short* l) {
  __builtin_amdgcn_global_load_lds(
      (const __attribute__((address_space(1))) unsigned int*)g,
      (__attribute__((address_space(3))) unsigned int*)l, 16, 0, 0);
}

// ---------------- f32 -> bf16 convert, 8 elems/thread ----------------
__global__ void cvt_kernel(const float* __restrict__ src,
                           unsigned short* __restrict__ dst, int n8) {
  int i = blockIdx.x * 256 + threadIdx.x;
  if (i >= n8) return;
  float8v v = reinterpret_cast<const float8v*>(src)[i];
  ushort8v h;
#pragma unroll
  for (int j = 0; j < 8; ++j) h[j] = f2b(v[j]);
  reinterpret_cast<ushort8v*>(dst)[i] = h;
}

// -------- weight transpose+convert: W(f32)[K][N] -> WT(bf16)[N][K] --------
__global__ __launch_bounds__(256) void wtrans_kernel(
    const float* __restrict__ W, unsigned short* __restrict__ WT,
    int K, int N) {
  __shared__ unsigned short T[64 * 72];
  const int tid = threadIdx.x;
  const int n0 = blockIdx.x * 64, k0 = blockIdx.y * 64;
#pragma unroll
  for (int it = 0; it < 2; ++it) {
    int c = tid + it * 256;               // [0,512)
    int r = c >> 3, cc = c & 7;
    float8v v = *reinterpret_cast<const float8v*>(
        &W[(size_t)(k0 + r) * N + n0 + cc * 8]);
    ushort8v h;
#pragma unroll
    for (int j = 0; j < 8; ++j) h[j] = f2b(v[j]);
    *reinterpret_cast<ushort8v*>(&T[r * 72 + cc * 8]) = h;
  }
  __syncthreads();
#pragma unroll
  for (int it = 0; it < 2; ++it) {
    int c = tid + it * 256;
    int n = c >> 3, kc = c & 7;
    ushort8v y;
#pragma unroll
    for (int j = 0; j < 8; ++j) y[j] = T[(kc * 8 + j) * 72 + n];
    *reinterpret_cast<ushort8v*>(&WT[(size_t)(n0 + n) * K + k0 + kc * 8]) = y;
  }
}

// ---------------- generic gemm_bt (single-buffer) ----------------
template <int TM, typename CT, bool ACC>
__global__ __launch_bounds__(256) void gemm_bt(
    const unsigned short* __restrict__ A, const unsigned short* __restrict__ Bt,
    CT* __restrict__ C, int M, int N, int K) {
  __shared__ unsigned short As[TM * 64];
  __shared__ unsigned short Bs[128 * 64];
  const int tid = threadIdx.x;
  const int m0 = blockIdx.y * TM, n0 = blockIdx.x * 128;
  const int wave = tid >> 6, lane = tid & 63;
  const int wm = (wave >> 1) * (TM / 2), wn = (wave & 1) * 64;
  const int l16 = lane & 15, quad = lane >> 4;
  constexpr int MI = TM / 32;

  f32x4 acc[MI][4];
#pragma unroll
  for (int i = 0; i < MI; ++i)
#pragma unroll
    for (int j = 0; j < 4; ++j)
#pragma unroll
      for (int r = 0; r < 4; ++r) acc[i][j][r] = 0.f;

  for (int k0 = 0; k0 < K; k0 += 64) {
    __syncthreads();
#pragma unroll
    for (int it = 0; it < TM * 8 / 256; ++it) {
      int c = it * 256 + tid;
      int m = c >> 3, kc = (c & 7) ^ (m & 7);
      g2lds16(&A[(size_t)(m0 + m) * K + k0 + kc * 8], &As[c * 8]);
    }
#pragma unroll
    for (int it = 0; it < 4; ++it) {
      int c = it * 256 + tid;
      int n = c >> 3, kc = (c & 7) ^ (n & 7);
      g2lds16(&Bt[(size_t)(n0 + n) * K + k0 + kc * 8], &Bs[c * 8]);
    }
    __syncthreads();

#pragma unroll
    for (int ks = 0; ks < 2; ++ks) {
      bf16x8 af[MI], bfr[4];
#pragma unroll
      for (int mi = 0; mi < MI; ++mi) {
        int m = wm + mi * 16 + l16;
        af[mi] = *reinterpret_cast<const bf16x8*>(
            &As[(m * 8 + ((ks * 4 + quad) ^ (m & 7))) * 8]);
      }
#pragma unroll
      for (int ni = 0; ni < 4; ++ni) {
        int n = wn + ni * 16 + l16;
        bfr[ni] = *reinterpret_cast<const bf16x8*>(
            &Bs[(n * 8 + ((ks * 4 + quad) ^ (n & 7))) * 8]);
      }
#pragma unroll
      for (int mi = 0; mi < MI; ++mi)
#pragma unroll
        for (int ni = 0; ni < 4; ++ni)
          acc[mi][ni] = __builtin_amdgcn_mfma_f32_16x16x32_bf16(
              af[mi], bfr[ni], acc[mi][ni], 0, 0, 0);
    }
  }

#pragma unroll
  for (int mi = 0; mi < MI; ++mi)
#pragma unroll
    for (int ni = 0; ni < 4; ++ni) {
      int row = m0 + wm + mi * 16 + quad * 4;
      int col = n0 + wn + ni * 16 + l16;
#pragma unroll
      for (int r = 0; r < 4; ++r) {
        size_t idx = (size_t)(row + r) * N + col;
        float val = acc[mi][ni][r];
        if constexpr (sizeof(CT) == 2) {
          if constexpr (ACC) val += b2f(C[idx]);
          C[idx] = f2b(val);
        } else {
          if constexpr (ACC) val += C[idx];
          C[idx] = val;
        }
      }
    }
}

// ------- fused GEMM #1: [q_r | k_r | c_kv] = X @ [wqr|wkr|wkvc]^T -------
__global__ __launch_bounds__(256) void gemm_fused3(
    const unsigned short* __restrict__ A, const unsigned short* __restrict__ Bt,
    unsigned short* __restrict__ Cq, unsigned short* __restrict__ Ck,
    unsigned short* __restrict__ Cc, int K) {
  __shared__ unsigned short As[1024 * 8];
  __shared__ unsigned short Bs[1024 * 8];
  const int tid = threadIdx.x;
  const int m0 = blockIdx.y * 128, n0 = blockIdx.x * 128;
  const int wave = tid >> 6, lane = tid & 63;
  const int wm = (wave >> 1) * 64, wn = (wave & 1) * 64;
  const int l16 = lane & 15, quad = lane >> 4;

  f32x4 acc[4][4];
#pragma unroll
  for (int i = 0; i < 4; ++i)
#pragma unroll
    for (int j = 0; j < 4; ++j)
#pragma unroll
      for (int r = 0; r < 4; ++r) acc[i][j][r] = 0.f;

  for (int k0 = 0; k0 < K; k0 += 64) {
    __syncthreads();
#pragma unroll
    for (int it = 0; it < 4; ++it) {
      int c = it * 256 + tid;
      int m = c >> 3, kc = (c & 7) ^ (m & 7);
      g2lds16(&A[(size_t)(m0 + m) * K + k0 + kc * 8], &As[c * 8]);
    }
#pragma unroll
    for (int it = 0; it < 4; ++it) {
      int c = it * 256 + tid;
      int n = c >> 3, kc = (c & 7) ^ (n & 7);
      g2lds16(&Bt[(size_t)(n0 + n) * K + k0 + kc * 8], &Bs[c * 8]);
    }
    __syncthreads();

#pragma unroll
    for (int ks = 0; ks < 2; ++ks) {
      bf16x8 af[4], bfr[4];
#pragma unroll
      for (int mi = 0; mi < 4; ++mi) {
        int m = wm + mi * 16 + l16;
        af[mi] = *reinterpret_cast<const bf16x8*>(
            &As[(m * 8 + ((ks * 4 + quad) ^ (m & 7))) * 8]);
      }
#pragma unroll
      for (int ni = 0; ni < 4; ++ni) {
        int n = wn + ni * 16 + l16;
        bfr[ni] = *reinterpret_cast<const bf16x8*>(
            &Bs[(n * 8 + ((ks * 4 + quad) ^ (n & 7))) * 8]);
      }
#pragma unroll
      for (int mi = 0; mi < 4; ++mi)
#pragma unroll
        for (int ni = 0; ni < 4; ++ni)
          acc[mi][ni] = __builtin_amdgcn_mfma_f32_16x16x32_bf16(
              af[mi], bfr[ni], acc[mi][ni], 0, 0, 0);
    }
  }

  unsigned short* dst;
  int w, cb;
  if (n0 < 1024)      { dst = Cq; w = 1024; cb = 0; }
  else if (n0 < 2048) { dst = Ck; w = 1024; cb = 1024; }
  else                { dst = Cc; w = 128;  cb = 2048; }
#pragma unroll
  for (int mi = 0; mi < 4; ++mi)
#pragma unroll
    for (int ni = 0; ni < 4; ++ni) {
      int row = m0 + wm + mi * 16 + quad * 4;
      int col = n0 - cb + wn + ni * 16 + l16;
#pragma unroll
      for (int r = 0; r < 4; ++r)
        dst[(size_t)(row + r) * w + col] = f2b(acc[mi][ni][r]);
    }
}

// ------- fused GEMM #2: [k_c(acc->ksb) | v_c] = ckv @ [wkc|wvc]^T -------
__global__ __launch_bounds__(256) void gemm_fused2(
    const unsigned short* __restrict__ A, const unsigned short* __restrict__ Bt,
    unsigned short* __restrict__ Ck, unsigned short* __restrict__ Cv, int K) {
  __shared__ unsigned short As[1024 * 8];
  __shared__ unsigned short Bs[1024 * 8];
  const int tid = threadIdx.x;
  const int m0 = blockIdx.y * 128, n0 = blockIdx.x * 128;
  const int wave = tid >> 6, lane = tid & 63;
  const int wm = (wave >> 1) * 64, wn = (wave & 1) * 64;
  const int l16 = lane & 15, quad = lane >> 4;

  f32x4 acc[4][4];
#pragma unroll
  for (int i = 0; i < 4; ++i)
#pragma unroll
    for (int j = 0; j < 4; ++j)
#pragma unroll
      for (int r = 0; r < 4; ++r) acc[i][j][r] = 0.f;

  for (int k0 = 0; k0 < K; k0 += 64) {
    __syncthreads();
#pragma unroll
    for (int it = 0; it < 4; ++it) {
      int c = it * 256 + tid;
      int m = c >> 3, kc = (c & 7) ^ (m & 7);
      g2lds16(&A[(size_t)(m0 + m) * K + k0 + kc * 8], &As[c * 8]);
    }
#pragma unroll
    for (int it = 0; it < 4; ++it) {
      int c = it * 256 + tid;
      int n = c >> 3, kc = (c & 7) ^ (n & 7);
      g2lds16(&Bt[(size_t)(n0 + n) * K + k0 + kc * 8], &Bs[c * 8]);
    }
    __syncthreads();

#pragma unroll
    for (int ks = 0; ks < 2; ++ks) {
      bf16x8 af[4], bfr[4];
#pragma unroll
      for (int mi = 0; mi < 4; ++mi) {
        int m = wm + mi * 16 + l16;
        af[mi] = *reinterpret_cast<const bf16x8*>(
            &As[(m * 8 + ((ks * 4 + quad) ^ (m & 7))) * 8]);
      }
#pragma unroll
      for (int ni = 0; ni < 4; ++ni) {
        int n = wn + ni * 16 + l16;
        bfr[ni] = *reinterpret_cast<const bf16x8*>(
            &Bs[(n * 8 + ((ks * 4 + quad) ^ (n & 7))) * 8]);
      }
#pragma unroll
      for (int mi = 0; mi < 4; ++mi)
#pragma unroll
        for (int ni = 0; ni < 4; ++ni)
          acc[mi][ni] = __builtin_amdgcn_mfma_f32_16x16x32_bf16(
              af[mi], bfr[ni], acc[mi][ni], 0, 0, 0);
    }
  }

  const bool first = (n0 < 1024);
  unsigned short* dst = first ? Ck : Cv;
  int cb = first ? 0 : 1024;
#pragma unroll
  for (int mi = 0; mi < 4; ++mi)
#pragma unroll
    for (int ni = 0; ni < 4; ++ni) {
      int row = m0 + wm + mi * 16 + quad * 4;
      int col = n0 - cb + wn + ni * 16 + l16;
#pragma unroll
      for (int r = 0; r < 4; ++r) {
        size_t idx = (size_t)(row + r) * 1024 + col;
        float val = acc[mi][ni][r];
        if (first) val += b2f(dst[idx]);   // accumulate onto rope'd k_r
        dst[idx] = f2b(val);
      }
    }
}

// ---------------- fused rope transform (in place) ----------------
// q additionally scaled by 0.125 * log2(e) so flash can use raw v_exp (exp2)
__global__ void rope_kernel(unsigned short* __restrict__ qr,
                            unsigned short* __restrict__ kr,
                            const float* __restrict__ tq,
                            const float* __restrict__ tk) {
  int idx = blockIdx.x * 256 + threadIdx.x;
  int i = idx & 31;
  int mh = idx >> 5;       // m*16 + h
  int m = mh >> 4;
  float f = exp2f(-(float)i * (13.287712379549449f / 32.f));  // 10000^(-i/32)
  float cq = cosf(tq[m] * f);
  float ck = cosf(tk[m] * f);
  size_t base = (size_t)mh * 64;
  const float qscale = 0.18033688011112042f;  // 0.125 * log2(e)
  float q1 = b2f(qr[base + i]), q2 = b2f(qr[base + i + 32]);
  float k1 = b2f(kr[base + i]), k2 = b2f(kr[base + i + 32]);
  qr[base + i]      = f2b((q1 * cq - q2 * ck) * qscale);
  qr[base + i + 32] = f2b((q2 * cq + q1 * ck) * qscale);
  kr[base + i]      = f2b(k1 * cq - k2 * ck);
  kr[base + i + 32] = f2b(k2 * cq + k1 * ck);
}

// ------ V transpose + key-permute: [b,l,h,d] -> Vt[b,h,d,sigma^-1(l)] ------
// sigma^-1: s = [k5 k3 k2 k4 k1 k0] (bits 5..0). Output position group g
// (8 consecutive s = g*8+e) gathers keys
//   key(g,e) = (g>>2)<<5 | (e>>2)<<4 | ((g>>1)&1)<<3 | (g&1)<<2 | (e&3)
// so each 16B store stays fully vectorized (b128), unlike the split-b64
// variant of R5.
__global__ __launch_bounds__(256) void vtrans_kernel(
    const unsigned short* __restrict__ v, unsigned short* __restrict__ vt,
    int L) {
  __shared__ unsigned short T[64 * 72];
  const int tid = threadIdx.x;
  const int l0 = blockIdx.x * 64, bh = blockIdx.y;
  const size_t inbase = ((size_t)(bh >> 4) * L) * 1024 + (bh & 15) * 64;
  const size_t outbase = (size_t)bh * 64 * L;
#pragma unroll
  for (int it = 0; it < 2; ++it) {
    int c = tid + it * 256;               // [0,512)
    int l = c >> 3, dc = c & 7;
    ushort8v x = *reinterpret_cast<const ushort8v*>(
        &v[inbase + (size_t)(l0 + l) * 1024 + dc * 8]);
    *reinterpret_cast<ushort8v*>(&T[l * 72 + dc * 8]) = x;
  }
  __syncthreads();
#pragma unroll
  for (int it = 0; it < 2; ++it) {
    int c = tid + it * 256;
    int d = c >> 3, g = c & 7;
    ushort8v y;
#pragma unroll
    for (int e = 0; e < 8; ++e) {
      int k = ((g >> 2) << 5) | ((e >> 2) << 4) | (((g >> 1) & 1) << 3) |
              ((g & 1) << 2) | (e & 3);
      y[e] = T[k * 72 + d];
    }
    *reinterpret_cast<ushort8v*>(&vt[outbase + (size_t)d * L + l0 + g * 8]) = y;
  }
}

// ---------- flash v14: flash13 + 2 m-tiles/wave (128 q per block) ----------
// LDS-read-BW fix: flash13's LDS pipe was 91% of wall time. Each wave now
// owns 32 q (2 m-tiles); K/V fragments are read from LDS ONCE and reused
// across both m-tiles -> LDS reads + staging traffic per q HALVE. Grid
// (L/128, NBH) = 512 blocks -> 2 blocks/CU, 8 waves/CU; cross-block overlap
// covers the dbuf staging drain. In-register P via sigma-renaming (flash13,
// proven), no fences, no P LDS.
__global__ __launch_bounds__(256) void flash14_kernel(
    const unsigned short* __restrict__ qs, const unsigned short* __restrict__ ks,
    const unsigned short* __restrict__ vt, unsigned short* __restrict__ o,
    int L) {
  __shared__ unsigned short Ks[2][512 * 8];   // 64 key x 64 d, swizzled (16KB)
  __shared__ unsigned short Vs[2][512 * 8];   // 64 d x 64 key(perm), swz (16KB)
  const int tid = threadIdx.x;
  const int wave = tid >> 6, lane = tid & 63;
  const int l16 = lane & 15, quad = lane >> 4;
  const int bh = blockIdx.y;                   // b*16 + h
  const int qb = blockIdx.x * 128 + wave * 32; // this wave's 32 q rows
  const size_t base = ((size_t)(bh >> 4) * L) * 1024 + (bh & 15) * 64;
  const size_t vtbase = (size_t)bh * 64 * L;

  bf16x8 aq[2][2];
#pragma unroll
  for (int mt = 0; mt < 2; ++mt) {
    size_t qrow = base + (size_t)(qb + mt * 16 + l16) * 1024;
    aq[mt][0] = *reinterpret_cast<const bf16x8*>(&qs[qrow + quad * 8]);
    aq[mt][1] = *reinterpret_cast<const bf16x8*>(&qs[qrow + 32 + quad * 8]);
  }

  ushort8v onesu;
#pragma unroll
  for (int j = 0; j < 8; ++j) onesu[j] = 0x3F80;  // bf16 1.0
  bf16x8 ones = *reinterpret_cast<bf16x8*>(&onesu);

  f32x4 oacc[2][4];
  f32x4 lacc[2];
#pragma unroll
  for (int mt = 0; mt < 2; ++mt) {
#pragma unroll
    for (int r = 0; r < 4; ++r) lacc[mt][r] = 0.f;
#pragma unroll
    for (int nt = 0; nt < 4; ++nt)
#pragma unroll
      for (int r = 0; r < 4; ++r) oacc[mt][nt][r] = 0.f;
  }

  const int T = L / 64;
  // prologue: stage tile 0 (256 threads -> 2 its per buffer)
#pragma unroll
  for (int it = 0; it < 2; ++it) {
    int c = it * 256 + tid;                   // [0,512)
    int key = c >> 3, dc = (c & 7) ^ (key & 7);
    g2lds16(&ks[base + (size_t)key * 1024 + dc * 8], &Ks[0][c * 8]);
  }
#pragma unroll
  for (int it = 0; it < 2; ++it) {
    int c = it * 256 + tid;
    int d = c >> 3, kc = (c & 7) ^ (d & 7);
    g2lds16(&vt[vtbase + (size_t)d * L + kc * 8], &Vs[0][c * 8]);
  }

  for (int t = 0; t < T; ++t) {
    __syncthreads();   // drains stage(t); prior-buf readers done
    if (t + 1 < T) {
      int k0 = (t + 1) * 64, nb = (t + 1) & 1;
#pragma unroll
      for (int it = 0; it < 2; ++it) {
        int c = it * 256 + tid;
        int key = c >> 3, dc = (c & 7) ^ (key & 7);
        g2lds16(&ks[base + (size_t)(k0 + key) * 1024 + dc * 8], &Ks[nb][c * 8]);
      }
#pragma unroll
      for (int it = 0; it < 2; ++it) {
        int c = it * 256 + tid;
        int d = c >> 3, kc = (c & 7) ^ (d & 7);
        g2lds16(&vt[vtbase + (size_t)d * L + k0 + kc * 8], &Vs[nb][c * 8]);
      }
    }
    const int cb = t & 1;

    // S^T = K Q^T for BOTH m-tiles; K fragments read once.
    // rows = key (quad*4+r), cols = q (l16).
    f32x4 st[2][4];
#pragma unroll
    for (int nt = 0; nt < 4; ++nt) {
      int key = nt * 16 + l16;
      int dc0 = quad ^ (key & 7);
      int dc1 = (4 + quad) ^ (key & 7);
      bf16x8 bk0 = *reinterpret_cast<const bf16x8*>(
          &Ks[cb][(key * 8 + dc0) * 8]);
      bf16x8 bk1 = *reinterpret_cast<const bf16x8*>(
          &Ks[cb][(key * 8 + dc1) * 8]);
#pragma unroll
      for (int mt = 0; mt < 2; ++mt) {
        f32x4 z; z[0] = z[1] = z[2] = z[3] = 0.f;
        z = __builtin_amdgcn_mfma_f32_16x16x32_bf16(bk0, aq[mt][0], z, 0, 0, 0);
        z = __builtin_amdgcn_mfma_f32_16x16x32_bf16(bk1, aq[mt][1], z, 0, 0, 0);
        st[mt][nt] = z;
      }
    }

    // exp2 -> ap frags by pure register renaming (key-permutation sigma):
    // ap[mt][hf] elems (2w, 2w+1) = exp2(st[mt][2hf + (w>>1)][2*(w&1) + {0,1}])
    bf16x8 ap[2][2];
#pragma unroll
    for (int mt = 0; mt < 2; ++mt) {
#pragma unroll
      for (int hf = 0; hf < 2; ++hf)
#pragma unroll
        for (int w = 0; w < 4; ++w) {
          int nt = 2 * hf + (w >> 1), p = w & 1;
          ap[mt][hf][2 * w] =
              (__bf16)__builtin_amdgcn_exp2f(st[mt][nt][2 * p]);
          ap[mt][hf][2 * w + 1] =
              (__bf16)__builtin_amdgcn_exp2f(st[mt][nt][2 * p + 1]);
        }
      lacc[mt] = __builtin_amdgcn_mfma_f32_16x16x32_bf16(ap[mt][0], ones,
                                                         lacc[mt], 0, 0, 0);
      lacc[mt] = __builtin_amdgcn_mfma_f32_16x16x32_bf16(ap[mt][1], ones,
                                                         lacc[mt], 0, 0, 0);
    }

    // O += P V (V fragments read once, reused by both m-tiles)
#pragma unroll
    for (int nt = 0; nt < 4; ++nt) {
      int d = nt * 16 + l16;
#pragma unroll
      for (int hf = 0; hf < 2; ++hf) {
        int kc = (hf * 4 + quad) ^ (d & 7);
        bf16x8 bv = *reinterpret_cast<const bf16x8*>(
            &Vs[cb][(d * 8 + kc) * 8]);
#pragma unroll
        for (int mt = 0; mt < 2; ++mt)
          oacc[mt][nt] = __builtin_amdgcn_mfma_f32_16x16x32_bf16(
              ap[mt][hf], bv, oacc[mt][nt], 0, 0, 0);
      }
    }
  }

#pragma unroll
  for (int mt = 0; mt < 2; ++mt)
#pragma unroll
    for (int r = 0; r < 4; ++r) {
      float inv = __builtin_amdgcn_rcpf(lacc[mt][r]);
      int q = qb + mt * 16 + quad * 4 + r;
#pragma unroll
      for (int nt = 0; nt < 4; ++nt)
        o[base + (size_t)q * 1024 + nt * 16 + l16] =
            f2b(oacc[mt][nt][r] * inv);
    }
}

// ---------------- driver ----------------
extern "C" void kernel_launch(void* const* d_in, const int* in_sizes, int n_in,
                              void* d_out, int out_size, void* d_ws, size_t ws_size,
                              hipStream_t stream) {
  const float* X    = (const float*)d_in[0];
  const float* tq   = (const float*)d_in[1];
  const float* tk   = (const float*)d_in[2];
  const float* wkvc = (const float*)d_in[3];
  const float* wkc  = (const float*)d_in[4];
  const float* wvc  = (const float*)d_in[5];
  const float* wqr  = (const float*)d_in[6];
  const float* wkr  = (const float*)d_in[7];
  const float* wo   = (const float*)d_in[8];

  const int D = 1024, DC = 128, L = 2048;
  const int M = in_sizes[0] / D;       // B*L
  const int B = M / L;
  const int NBH = B * 16;
  (void)n_in; (void)out_size; (void)ws_size;

  unsigned short* p = (unsigned short*)d_ws;
  auto take = [&](size_t n) { unsigned short* r = p; p += n; return r; };
  unsigned short* Xb    = take((size_t)M * D);
  unsigned short* qsb   = take((size_t)M * D);
  unsigned short* ksb   = take((size_t)M * D);
  unsigned short* vcb   = take((size_t)M * D);
  unsigned short* ckv   = take((size_t)M * DC);
  unsigned short* Wbig  = take((size_t)(2 * D + DC) * D);   // [wqr|wkr|wkvc]^T
  unsigned short* Wkcvc = take((size_t)(2 * D) * DC);       // [wkc|wvc]^T
  unsigned short* WoT   = take((size_t)D * D);
  unsigned short* vtb   = Xb;   // Xb dead after fused3 gemm
  unsigned short* obuf  = vcb;  // vcb dead after vtrans; flash O lands here

  // prep
  cvt_kernel<<<(M * D / 8 + 255) / 256, 256, 0, stream>>>(X, Xb, M * D / 8);
  auto wt = [&](const float* W, unsigned short* WT, int K, int N) {
    dim3 g(N / 64, K / 64);
    wtrans_kernel<<<g, 256, 0, stream>>>(W, WT, K, N);
  };
  wt(wqr,  Wbig,                          D, D);
  wt(wkr,  Wbig + (size_t)D * D,          D, D);
  wt(wkvc, Wbig + (size_t)2 * D * D,      D, DC);
  wt(wkc,  Wkcvc,                         DC, D);
  wt(wvc,  Wkcvc + (size_t)D * DC,        DC, D);
  wt(wo,   WoT,                           D, D);

  {
    dim3 g((2 * D + DC) / 128, M / 128);                   // (17, 32)
    gemm_fused3<<<g, 256, 0, stream>>>(Xb, Wbig, qsb, ksb, ckv, D);
  }
  rope_kernel<<<(M * 512) / 256, 256, 0, stream>>>(qsb, ksb, tq, tk);
  {
    dim3 g(2 * D / 128, M / 128);                          // (16, 32)
    gemm_fused2<<<g, 256, 0, stream>>>(ckv, Wkcvc, ksb, vcb, DC);
  }

  dim3 tg(L / 64, NBH);
  vtrans_kernel<<<tg, 256, 0, stream>>>(vcb, vtb, L);

  dim3 fg(L / 128, NBH);                                   // (16, 32)
  flash14_kernel<<<fg, 256, 0, stream>>>(qsb, ksb, vtb, obuf, L);

  {
    dim3 g(D / 128, M / 64);                               // (8, 64)
    gemm_bt<64, float, false><<<g, 256, 0, stream>>>(
        obuf, WoT, (float*)d_out, M, D, D);
  }
}

// Round 7
// 222.006 us; speedup vs baseline: 1.4047x; 1.0181x over previous
//
#include <hip/hip_runtime.h>

typedef float          f32x4    __attribute__((ext_vector_type(4)));
typedef float          float8v  __attribute__((ext_vector_type(8)));
typedef unsigned short ushort8v __attribute__((ext_vector_type(8)));
typedef __bf16         bf16x8   __attribute__((ext_vector_type(8)));

__device__ __forceinline__ unsigned short f2b(float x) {
  union { __bf16 b; unsigned short u; } v;
  v.b = (__bf16)x;                       // hw v_cvt (RNE) on gfx950
  return v.u;
}
__device__ __forceinline__ float b2f(unsigned short h) {
  union { unsigned u; float f; } v; v.u = ((unsigned)h) << 16;
  return v.f;
}

// async global->LDS, 16B per lane; LDS dest = wave-uniform base + lane*16
__device__ __forceinline__ void g2lds16(const unsigned short* g,
                                        unsigned short* l) {
  __builtin_amdgcn_global_load_lds(
      (const __attribute__((address_space(1))) unsigned int*)g,
      (__attribute__((address_space(3))) unsigned int*)l, 16, 0, 0);
}

// ---------------- f32 -> bf16 convert, 8 elems/thread ----------------
__global__ void cvt_kernel(const float* __restrict__ src,
                           unsigned short* __restrict__ dst, int n8) {
  int i = blockIdx.x * 256 + threadIdx.x;
  if (i >= n8) return;
  float8v v = reinterpret_cast<const float8v*>(src)[i];
  ushort8v h;
#pragma unroll
  for (int j = 0; j < 8; ++j) h[j] = f2b(v[j]);
  reinterpret_cast<ushort8v*>(dst)[i] = h;
}

// -------- weight transpose+convert: W(f32)[K][N] -> WT(bf16)[N][K] --------
__global__ __launch_bounds__(256) void wtrans_kernel(
    const float* __restrict__ W, unsigned short* __restrict__ WT,
    int K, int N) {
  __shared__ unsigned short T[64 * 72];
  const int tid = threadIdx.x;
  const int n0 = blockIdx.x * 64, k0 = blockIdx.y * 64;
#pragma unroll
  for (int it = 0; it < 2; ++it) {
    int c = tid + it * 256;               // [0,512)
    int r = c >> 3, cc = c & 7;
    float8v v = *reinterpret_cast<const float8v*>(
        &W[(size_t)(k0 + r) * N + n0 + cc * 8]);
    ushort8v h;
#pragma unroll
    for (int j = 0; j < 8; ++j) h[j] = f2b(v[j]);
    *reinterpret_cast<ushort8v*>(&T[r * 72 + cc * 8]) = h;
  }
  __syncthreads();
#pragma unroll
  for (int it = 0; it < 2; ++it) {
    int c = tid + it * 256;
    int n = c >> 3, kc = c & 7;
    ushort8v y;
#pragma unroll
    for (int j = 0; j < 8; ++j) y[j] = T[(kc * 8 + j) * 72 + n];
    *reinterpret_cast<ushort8v*>(&WT[(size_t)(n0 + n) * K + k0 + kc * 8]) = y;
  }
}

// ---------------- generic gemm_bt (single-buffer) ----------------
template <int TM, typename CT, bool ACC>
__global__ __launch_bounds__(256) void gemm_bt(
    const unsigned short* __restrict__ A, const unsigned short* __restrict__ Bt,
    CT* __restrict__ C, int M, int N, int K) {
  __shared__ unsigned short As[TM * 64];
  __shared__ unsigned short Bs[128 * 64];
  const int tid = threadIdx.x;
  const int m0 = blockIdx.y * TM, n0 = blockIdx.x * 128;
  const int wave = tid >> 6, lane = tid & 63;
  const int wm = (wave >> 1) * (TM / 2), wn = (wave & 1) * 64;
  const int l16 = lane & 15, quad = lane >> 4;
  constexpr int MI = TM / 32;

  f32x4 acc[MI][4];
#pragma unroll
  for (int i = 0; i < MI; ++i)
#pragma unroll
    for (int j = 0; j < 4; ++j)
#pragma unroll
      for (int r = 0; r < 4; ++r) acc[i][j][r] = 0.f;

  for (int k0 = 0; k0 < K; k0 += 64) {
    __syncthreads();
#pragma unroll
    for (int it = 0; it < TM * 8 / 256; ++it) {
      int c = it * 256 + tid;
      int m = c >> 3, kc = (c & 7) ^ (m & 7);
      g2lds16(&A[(size_t)(m0 + m) * K + k0 + kc * 8], &As[c * 8]);
    }
#pragma unroll
    for (int it = 0; it < 4; ++it) {
      int c = it * 256 + tid;
      int n = c >> 3, kc = (c & 7) ^ (n & 7);
      g2lds16(&Bt[(size_t)(n0 + n) * K + k0 + kc * 8], &Bs[c * 8]);
    }
    __syncthreads();

#pragma unroll
    for (int ks = 0; ks < 2; ++ks) {
      bf16x8 af[MI], bfr[4];
#pragma unroll
      for (int mi = 0; mi < MI; ++mi) {
        int m = wm + mi * 16 + l16;
        af[mi] = *reinterpret_cast<const bf16x8*>(
            &As[(m * 8 + ((ks * 4 + quad) ^ (m & 7))) * 8]);
      }
#pragma unroll
      for (int ni = 0; ni < 4; ++ni) {
        int n = wn + ni * 16 + l16;
        bfr[ni] = *reinterpret_cast<const bf16x8*>(
            &Bs[(n * 8 + ((ks * 4 + quad) ^ (n & 7))) * 8]);
      }
#pragma unroll
      for (int mi = 0; mi < MI; ++mi)
#pragma unroll
        for (int ni = 0; ni < 4; ++ni)
          acc[mi][ni] = __builtin_amdgcn_mfma_f32_16x16x32_bf16(
              af[mi], bfr[ni], acc[mi][ni], 0, 0, 0);
    }
  }

#pragma unroll
  for (int mi = 0; mi < MI; ++mi)
#pragma unroll
    for (int ni = 0; ni < 4; ++ni) {
      int row = m0 + wm + mi * 16 + quad * 4;
      int col = n0 + wn + ni * 16 + l16;
#pragma unroll
      for (int r = 0; r < 4; ++r) {
        size_t idx = (size_t)(row + r) * N + col;
        float val = acc[mi][ni][r];
        if constexpr (sizeof(CT) == 2) {
          if constexpr (ACC) val += b2f(C[idx]);
          C[idx] = f2b(val);
        } else {
          if constexpr (ACC) val += C[idx];
          C[idx] = val;
        }
      }
    }
}

// ------- fused GEMM #1: [q_r | k_r | c_kv] = X @ [wqr|wkr|wkvc]^T -------
__global__ __launch_bounds__(256) void gemm_fused3(
    const unsigned short* __restrict__ A, const unsigned short* __restrict__ Bt,
    unsigned short* __restrict__ Cq, unsigned short* __restrict__ Ck,
    unsigned short* __restrict__ Cc, int K) {
  __shared__ unsigned short As[1024 * 8];
  __shared__ unsigned short Bs[1024 * 8];
  const int tid = threadIdx.x;
  const int m0 = blockIdx.y * 128, n0 = blockIdx.x * 128;
  const int wave = tid >> 6, lane = tid & 63;
  const int wm = (wave >> 1) * 64, wn = (wave & 1) * 64;
  const int l16 = lane & 15, quad = lane >> 4;

  f32x4 acc[4][4];
#pragma unroll
  for (int i = 0; i < 4; ++i)
#pragma unroll
    for (int j = 0; j < 4; ++j)
#pragma unroll
      for (int r = 0; r < 4; ++r) acc[i][j][r] = 0.f;

  for (int k0 = 0; k0 < K; k0 += 64) {
    __syncthreads();
#pragma unroll
    for (int it = 0; it < 4; ++it) {
      int c = it * 256 + tid;
      int m = c >> 3, kc = (c & 7) ^ (m & 7);
      g2lds16(&A[(size_t)(m0 + m) * K + k0 + kc * 8], &As[c * 8]);
    }
#pragma unroll
    for (int it = 0; it < 4; ++it) {
      int c = it * 256 + tid;
      int n = c >> 3, kc = (c & 7) ^ (n & 7);
      g2lds16(&Bt[(size_t)(n0 + n) * K + k0 + kc * 8], &Bs[c * 8]);
    }
    __syncthreads();

#pragma unroll
    for (int ks = 0; ks < 2; ++ks) {
      bf16x8 af[4], bfr[4];
#pragma unroll
      for (int mi = 0; mi < 4; ++mi) {
        int m = wm + mi * 16 + l16;
        af[mi] = *reinterpret_cast<const bf16x8*>(
            &As[(m * 8 + ((ks * 4 + quad) ^ (m & 7))) * 8]);
      }
#pragma unroll
      for (int ni = 0; ni < 4; ++ni) {
        int n = wn + ni * 16 + l16;
        bfr[ni] = *reinterpret_cast<const bf16x8*>(
            &Bs[(n * 8 + ((ks * 4 + quad) ^ (n & 7))) * 8]);
      }
#pragma unroll
      for (int mi = 0; mi < 4; ++mi)
#pragma unroll
        for (int ni = 0; ni < 4; ++ni)
          acc[mi][ni] = __builtin_amdgcn_mfma_f32_16x16x32_bf16(
              af[mi], bfr[ni], acc[mi][ni], 0, 0, 0);
    }
  }

  unsigned short* dst;
  int w, cb;
  if (n0 < 1024)      { dst = Cq; w = 1024; cb = 0; }
  else if (n0 < 2048) { dst = Ck; w = 1024; cb = 1024; }
  else                { dst = Cc; w = 128;  cb = 2048; }
#pragma unroll
  for (int mi = 0; mi < 4; ++mi)
#pragma unroll
    for (int ni = 0; ni < 4; ++ni) {
      int row = m0 + wm + mi * 16 + quad * 4;
      int col = n0 - cb + wn + ni * 16 + l16;
#pragma unroll
      for (int r = 0; r < 4; ++r)
        dst[(size_t)(row + r) * w + col] = f2b(acc[mi][ni][r]);
    }
}

// ------- fused GEMM #2: [k_c(acc->ksb) | v_c] = ckv @ [wkc|wvc]^T -------
__global__ __launch_bounds__(256) void gemm_fused2(
    const unsigned short* __restrict__ A, const unsigned short* __restrict__ Bt,
    unsigned short* __restrict__ Ck, unsigned short* __restrict__ Cv, int K) {
  __shared__ unsigned short As[1024 * 8];
  __shared__ unsigned short Bs[1024 * 8];
  const int tid = threadIdx.x;
  const int m0 = blockIdx.y * 128, n0 = blockIdx.x * 128;
  const int wave = tid >> 6, lane = tid & 63;
  const int wm = (wave >> 1) * 64, wn = (wave & 1) * 64;
  const int l16 = lane & 15, quad = lane >> 4;

  f32x4 acc[4][4];
#pragma unroll
  for (int i = 0; i < 4; ++i)
#pragma unroll
    for (int j = 0; j < 4; ++j)
#pragma unroll
      for (int r = 0; r < 4; ++r) acc[i][j][r] = 0.f;

  for (int k0 = 0; k0 < K; k0 += 64) {
    __syncthreads();
#pragma unroll
    for (int it = 0; it < 4; ++it) {
      int c = it * 256 + tid;
      int m = c >> 3, kc = (c & 7) ^ (m & 7);
      g2lds16(&A[(size_t)(m0 + m) * K + k0 + kc * 8], &As[c * 8]);
    }
#pragma unroll
    for (int it = 0; it < 4; ++it) {
      int c = it * 256 + tid;
      int n = c >> 3, kc = (c & 7) ^ (n & 7);
      g2lds16(&Bt[(size_t)(n0 + n) * K + k0 + kc * 8], &Bs[c * 8]);
    }
    __syncthreads();

#pragma unroll
    for (int ks = 0; ks < 2; ++ks) {
      bf16x8 af[4], bfr[4];
#pragma unroll
      for (int mi = 0; mi < 4; ++mi) {
        int m = wm + mi * 16 + l16;
        af[mi] = *reinterpret_cast<const bf16x8*>(
            &As[(m * 8 + ((ks * 4 + quad) ^ (m & 7))) * 8]);
      }
#pragma unroll
      for (int ni = 0; ni < 4; ++ni) {
        int n = wn + ni * 16 + l16;
        bfr[ni] = *reinterpret_cast<const bf16x8*>(
            &Bs[(n * 8 + ((ks * 4 + quad) ^ (n & 7))) * 8]);
      }
#pragma unroll
      for (int mi = 0; mi < 4; ++mi)
#pragma unroll
        for (int ni = 0; ni < 4; ++ni)
          acc[mi][ni] = __builtin_amdgcn_mfma_f32_16x16x32_bf16(
              af[mi], bfr[ni], acc[mi][ni], 0, 0, 0);
    }
  }

  const bool first = (n0 < 1024);
  unsigned short* dst = first ? Ck : Cv;
  int cb = first ? 0 : 1024;
#pragma unroll
  for (int mi = 0; mi < 4; ++mi)
#pragma unroll
    for (int ni = 0; ni < 4; ++ni) {
      int row = m0 + wm + mi * 16 + quad * 4;
      int col = n0 - cb + wn + ni * 16 + l16;
#pragma unroll
      for (int r = 0; r < 4; ++r) {
        size_t idx = (size_t)(row + r) * 1024 + col;
        float val = acc[mi][ni][r];
        if (first) val += b2f(dst[idx]);   // accumulate onto rope'd k_r
        dst[idx] = f2b(val);
      }
    }
}

// ---------------- fused rope transform (in place) ----------------
// q additionally scaled by 0.125 * log2(e) so flash can use raw v_exp (exp2)
__global__ void rope_kernel(unsigned short* __restrict__ qr,
                            unsigned short* __restrict__ kr,
                            const float* __restrict__ tq,
                            const float* __restrict__ tk) {
  int idx = blockIdx.x * 256 + threadIdx.x;
  int i = idx & 31;
  int mh = idx >> 5;       // m*16 + h
  int m = mh >> 4;
  float f = exp2f(-(float)i * (13.287712379549449f / 32.f));  // 10000^(-i/32)
  float cq = cosf(tq[m] * f);
  float ck = cosf(tk[m] * f);
  size_t base = (size_t)mh * 64;
  const float qscale = 0.18033688011112042f;  // 0.125 * log2(e)
  float q1 = b2f(qr[base + i]), q2 = b2f(qr[base + i + 32]);
  float k1 = b2f(kr[base + i]), k2 = b2f(kr[base + i + 32]);
  qr[base + i]      = f2b((q1 * cq - q2 * ck) * qscale);
  qr[base + i + 32] = f2b((q2 * cq + q1 * ck) * qscale);
  kr[base + i]      = f2b(k1 * cq - k2 * ck);
  kr[base + i + 32] = f2b(k2 * cq + k1 * ck);
}

// ------ V transpose + key-permute: [b,l,h,d] -> Vt[b,h,d,sigma^-1(l)] ------
// sigma^-1: s = [k5 k3 k2 k4 k1 k0] (bits 5..0). Output position group g
// (8 consecutive s = g*8+e) gathers keys
//   key(g,e) = (g>>2)<<5 | (e>>2)<<4 | ((g>>1)&1)<<3 | (g&1)<<2 | (e&3)
// so each 16B store stays fully vectorized (b128).
__global__ __launch_bounds__(256) void vtrans_kernel(
    const unsigned short* __restrict__ v, unsigned short* __restrict__ vt,
    int L) {
  __shared__ unsigned short T[64 * 72];
  const int tid = threadIdx.x;
  const int l0 = blockIdx.x * 64, bh = blockIdx.y;
  const size_t inbase = ((size_t)(bh >> 4) * L) * 1024 + (bh & 15) * 64;
  const size_t outbase = (size_t)bh * 64 * L;
#pragma unroll
  for (int it = 0; it < 2; ++it) {
    int c = tid + it * 256;               // [0,512)
    int l = c >> 3, dc = c & 7;
    ushort8v x = *reinterpret_cast<const ushort8v*>(
        &v[inbase + (size_t)(l0 + l) * 1024 + dc * 8]);
    *reinterpret_cast<ushort8v*>(&T[l * 72 + dc * 8]) = x;
  }
  __syncthreads();
#pragma unroll
  for (int it = 0; it < 2; ++it) {
    int c = tid + it * 256;
    int d = c >> 3, g = c & 7;
    ushort8v y;
#pragma unroll
    for (int e = 0; e < 8; ++e) {
      int k = ((g >> 2) << 5) | ((e >> 2) << 4) | (((g >> 1) & 1) << 3) |
              ((g & 1) << 2) | (e & 3);
      y[e] = T[k * 72 + d];
    }
    *reinterpret_cast<ushort8v*>(&vt[outbase + (size_t)d * L + l0 + g * 8]) = y;
  }
}

// ---------- flash v15: flash14 + in-block KV-split (8 waves, 512 thr) ----
// flash14 was latency-exposed: grid (512 blocks) capped occupancy at 8
// waves/CU. Now 512-thread blocks: waves 0-3 process KV [0,L/2), waves 4-7
// KV [L/2,L), same 128 q rows, identical per-wave loop (16 dbuf steps).
// No max-subtraction -> O and l are additive over key ranges: half-1 waves
// write (oacc,lacc) to LDS once at the end; half-0 adds, normalizes,
// stores. 64KB LDS -> 2 blocks/CU -> 16 waves/CU = 4/SIMD.
__global__ __launch_bounds__(512) void flash15_kernel(
    const unsigned short* __restrict__ qs, const unsigned short* __restrict__ ks,
    const unsigned short* __restrict__ vt, unsigned short* __restrict__ o,
    int L) {
  // [kv={K,V}][half][dbuf][64x64 swizzled]  = 64KB total
  __shared__ unsigned short KV[2][2][2][512 * 8];
  const int tid = threadIdx.x;
  const int wave = tid >> 6, lane = tid & 63;
  const int half = wave >> 2;                  // KV half this wave works on
  const int l16 = lane & 15, quad = lane >> 4;
  const int bh = blockIdx.y;                   // b*16 + h
  const int qb = blockIdx.x * 128 + (wave & 3) * 32;  // this wave's 32 q rows
  const size_t base = ((size_t)(bh >> 4) * L) * 1024 + (bh & 15) * 64;
  const size_t vtbase = (size_t)bh * 64 * L;
  const int kvoff = half * (L >> 1);           // key offset of this half
  const int sid = tid & 255;                   // staging lane within half

  bf16x8 aq[2][2];
#pragma unroll
  for (int mt = 0; mt < 2; ++mt) {
    size_t qrow = base + (size_t)(qb + mt * 16 + l16) * 1024;
    aq[mt][0] = *reinterpret_cast<const bf16x8*>(&qs[qrow + quad * 8]);
    aq[mt][1] = *reinterpret_cast<const bf16x8*>(&qs[qrow + 32 + quad * 8]);
  }

  ushort8v onesu;
#pragma unroll
  for (int j = 0; j < 8; ++j) onesu[j] = 0x3F80;  // bf16 1.0
  bf16x8 ones = *reinterpret_cast<bf16x8*>(&onesu);

  f32x4 oacc[2][4];
  f32x4 lacc[2];
#pragma unroll
  for (int mt = 0; mt < 2; ++mt) {
#pragma unroll
    for (int r = 0; r < 4; ++r) lacc[mt][r] = 0.f;
#pragma unroll
    for (int nt = 0; nt < 4; ++nt)
#pragma unroll
      for (int r = 0; r < 4; ++r) oacc[mt][nt][r] = 0.f;
  }

  const int T = L / 128;   // 16 tiles per half
  // prologue: each half's 256 threads stage that half's tile 0
#pragma unroll
  for (int it = 0; it < 2; ++it) {
    int c = it * 256 + sid;                    // [0,512)
    int key = c >> 3, dc = (c & 7) ^ (key & 7);
    g2lds16(&ks[base + (size_t)(kvoff + key) * 1024 + dc * 8],
            &KV[0][half][0][c * 8]);
  }
#pragma unroll
  for (int it = 0; it < 2; ++it) {
    int c = it * 256 + sid;
    int d = c >> 3, kc = (c & 7) ^ (d & 7);
    g2lds16(&vt[vtbase + (size_t)d * L + kvoff + kc * 8],
            &KV[1][half][0][c * 8]);
  }

  for (int t = 0; t < T; ++t) {
    __syncthreads();   // drains stage(t); prior-buf readers done
    if (t + 1 < T) {
      int k0 = kvoff + (t + 1) * 64, nb = (t + 1) & 1;
#pragma unroll
      for (int it = 0; it < 2; ++it) {
        int c = it * 256 + sid;
        int key = c >> 3, dc = (c & 7) ^ (key & 7);
        g2lds16(&ks[base + (size_t)(k0 + key) * 1024 + dc * 8],
                &KV[0][half][nb][c * 8]);
      }
#pragma unroll
      for (int it = 0; it < 2; ++it) {
        int c = it * 256 + sid;
        int d = c >> 3, kc = (c & 7) ^ (d & 7);
        g2lds16(&vt[vtbase + (size_t)d * L + k0 + kc * 8],
                &KV[1][half][nb][c * 8]);
      }
    }
    const int cb = t & 1;
    const unsigned short* Ks = &KV[0][half][cb][0];
    const unsigned short* Vs = &KV[1][half][cb][0];

    // S^T = K Q^T for BOTH m-tiles; K fragments read once.
    f32x4 st[2][4];
#pragma unroll
    for (int nt = 0; nt < 4; ++nt) {
      int key = nt * 16 + l16;
      int dc0 = quad ^ (key & 7);
      int dc1 = (4 + quad) ^ (key & 7);
      bf16x8 bk0 = *reinterpret_cast<const bf16x8*>(&Ks[(key * 8 + dc0) * 8]);
      bf16x8 bk1 = *reinterpret_cast<const bf16x8*>(&Ks[(key * 8 + dc1) * 8]);
#pragma unroll
      for (int mt = 0; mt < 2; ++mt) {
        f32x4 z; z[0] = z[1] = z[2] = z[3] = 0.f;
        z = __builtin_amdgcn_mfma_f32_16x16x32_bf16(bk0, aq[mt][0], z, 0, 0, 0);
        z = __builtin_amdgcn_mfma_f32_16x16x32_bf16(bk1, aq[mt][1], z, 0, 0, 0);
        st[mt][nt] = z;
      }
    }

    // exp2 -> ap frags by pure register renaming (key-permutation sigma)
    bf16x8 ap[2][2];
#pragma unroll
    for (int mt = 0; mt < 2; ++mt) {
#pragma unroll
      for (int hf = 0; hf < 2; ++hf)
#pragma unroll
        for (int w = 0; w < 4; ++w) {
          int nt = 2 * hf + (w >> 1), p = w & 1;
          ap[mt][hf][2 * w] =
              (__bf16)__builtin_amdgcn_exp2f(st[mt][nt][2 * p]);
          ap[mt][hf][2 * w + 1] =
              (__bf16)__builtin_amdgcn_exp2f(st[mt][nt][2 * p + 1]);
        }
      lacc[mt] = __builtin_amdgcn_mfma_f32_16x16x32_bf16(ap[mt][0], ones,
                                                         lacc[mt], 0, 0, 0);
      lacc[mt] = __builtin_amdgcn_mfma_f32_16x16x32_bf16(ap[mt][1], ones,
                                                         lacc[mt], 0, 0, 0);
    }

    // O += P V (V fragments read once, reused by both m-tiles)
#pragma unroll
    for (int nt = 0; nt < 4; ++nt) {
      int d = nt * 16 + l16;
#pragma unroll
      for (int hf = 0; hf < 2; ++hf) {
        int kc = (hf * 4 + quad) ^ (d & 7);
        bf16x8 bv = *reinterpret_cast<const bf16x8*>(&Vs[(d * 8 + kc) * 8]);
#pragma unroll
        for (int mt = 0; mt < 2; ++mt)
          oacc[mt][nt] = __builtin_amdgcn_mfma_f32_16x16x32_bf16(
              ap[mt][hf], bv, oacc[mt][nt], 0, 0, 0);
      }
    }
  }

  // ---- combine halves in LDS (O and l are additive; no max used) ----
  __syncthreads();                 // all K/V reads done; LDS reusable
  float* cbuf = (float*)&KV[0][0][0][0];   // 45056B needed <= 64KB
  if (half == 1) {
    int slot = ((wave - 4) * 64 + lane) * 44;   // stride 44 f32 = 176B (16B-aligned)
#pragma unroll
    for (int mt = 0; mt < 2; ++mt) {
#pragma unroll
      for (int nt = 0; nt < 4; ++nt)
        *reinterpret_cast<f32x4*>(&cbuf[slot + (mt * 4 + nt) * 4]) =
            oacc[mt][nt];
      *reinterpret_cast<f32x4*>(&cbuf[slot + 32 + mt * 4]) = lacc[mt];
    }
  }
  __syncthreads();
  if (half == 0) {
    int slot = (wave * 64 + lane) * 44;
#pragma unroll
    for (int mt = 0; mt < 2; ++mt) {
#pragma unroll
      for (int nt = 0; nt < 4; ++nt) {
        f32x4 ov = *reinterpret_cast<const f32x4*>(
            &cbuf[slot + (mt * 4 + nt) * 4]);
#pragma unroll
        for (int r = 0; r < 4; ++r) oacc[mt][nt][r] += ov[r];
      }
      f32x4 lv = *reinterpret_cast<const f32x4*>(&cbuf[slot + 32 + mt * 4]);
#pragma unroll
      for (int r = 0; r < 4; ++r) lacc[mt][r] += lv[r];
    }
#pragma unroll
    for (int mt = 0; mt < 2; ++mt)
#pragma unroll
      for (int r = 0; r < 4; ++r) {
        float inv = __builtin_amdgcn_rcpf(lacc[mt][r]);
        int q = qb + mt * 16 + quad * 4 + r;
#pragma unroll
        for (int nt = 0; nt < 4; ++nt)
          o[base + (size_t)q * 1024 + nt * 16 + l16] =
              f2b(oacc[mt][nt][r] * inv);
      }
  }
}

// ---------------- driver ----------------
extern "C" void kernel_launch(void* const* d_in, const int* in_sizes, int n_in,
                              void* d_out, int out_size, void* d_ws, size_t ws_size,
                              hipStream_t stream) {
  const float* X    = (const float*)d_in[0];
  const float* tq   = (const float*)d_in[1];
  const float* tk   = (const float*)d_in[2];
  const float* wkvc = (const float*)d_in[3];
  const float* wkc  = (const float*)d_in[4];
  const float* wvc  = (const float*)d_in[5];
  const float* wqr  = (const float*)d_in[6];
  const float* wkr  = (const float*)d_in[7];
  const float* wo   = (const float*)d_in[8];

  const int D = 1024, DC = 128, L = 2048;
  const int M = in_sizes[0] / D;       // B*L
  const int B = M / L;
  const int NBH = B * 16;
  (void)n_in; (void)out_size; (void)ws_size;

  unsigned short* p = (unsigned short*)d_ws;
  auto take = [&](size_t n) { unsigned short* r = p; p += n; return r; };
  unsigned short* Xb    = take((size_t)M * D);
  unsigned short* qsb   = take((size_t)M * D);
  unsigned short* ksb   = take((size_t)M * D);
  unsigned short* vcb   = take((size_t)M * D);
  unsigned short* ckv   = take((size_t)M * DC);
  unsigned short* Wbig  = take((size_t)(2 * D + DC) * D);   // [wqr|wkr|wkvc]^T
  unsigned short* Wkcvc = take((size_t)(2 * D) * DC);       // [wkc|wvc]^T
  unsigned short* WoT   = take((size_t)D * D);
  unsigned short* vtb   = Xb;   // Xb dead after fused3 gemm
  unsigned short* obuf  = vcb;  // vcb dead after vtrans; flash O lands here

  // prep
  cvt_kernel<<<(M * D / 8 + 255) / 256, 256, 0, stream>>>(X, Xb, M * D / 8);
  auto wt = [&](const float* W, unsigned short* WT, int K, int N) {
    dim3 g(N / 64, K / 64);
    wtrans_kernel<<<g, 256, 0, stream>>>(W, WT, K, N);
  };
  wt(wqr,  Wbig,                          D, D);
  wt(wkr,  Wbig + (size_t)D * D,          D, D);
  wt(wkvc, Wbig + (size_t)2 * D * D,      D, DC);
  wt(wkc,  Wkcvc,                         DC, D);
  wt(wvc,  Wkcvc + (size_t)D * DC,        DC, D);
  wt(wo,   WoT,                           D, D);

  {
    dim3 g((2 * D + DC) / 128, M / 128);                   // (17, 32)
    gemm_fused3<<<g, 256, 0, stream>>>(Xb, Wbig, qsb, ksb, ckv, D);
  }
  rope_kernel<<<(M * 512) / 256, 256, 0, stream>>>(qsb, ksb, tq, tk);
  {
    dim3 g(2 * D / 128, M / 128);                          // (16, 32)
    gemm_fused2<<<g, 256, 0, stream>>>(ckv, Wkcvc, ksb, vcb, DC);
  }

  dim3 tg(L / 64, NBH);
  vtrans_kernel<<<tg, 256, 0, stream>>>(vcb, vtb, L);

  dim3 fg(L / 128, NBH);                                   // (16, 32)
  flash15_kernel<<<fg, 512, 0, stream>>>(qsb, ksb, vtb, obuf, L);

  {
    dim3 g(D / 128, M / 64);                               // (8, 64)
    gemm_bt<64, float, false><<<g, 256, 0, stream>>>(
        obuf, WoT, (float*)d_out, M, D, D);
  }
}